// Round 8
// baseline (116.360 us; speedup 1.0000x reference)
//
#include <hip/hip_runtime.h>
#include <hip/hip_bf16.h>

typedef __attribute__((ext_vector_type(8)))  short short8;
typedef __attribute__((ext_vector_type(4)))  short short4v;
typedef __attribute__((ext_vector_type(4)))  float f32x4;

static __device__ inline short f2bf(float f) {
    union { __hip_bfloat16 h; unsigned short u; } cv;
    cv.h = __float2bfloat16(f);
    return (short)cv.u;
}

typedef __attribute__((address_space(3))) void lds_void;
typedef const __attribute__((address_space(1))) void glob_void;
static __device__ inline void gl16(const void* g, void* l) {
    // global -> LDS direct copy, 16 B/lane (1 KiB/wave). LDS dest must be
    // wave-uniform base (+ lane*16 HW-added); global src is per-lane.
    __builtin_amdgcn_global_load_lds((glob_void*)g, (lds_void*)l, 16, 0, 0);
}

// ---------------------------------------------------------------------------
// Kernel 0: zero halo of padded [nimg][66][rs][ch8*8] bf16 buffer (cols 0..65).
// ---------------------------------------------------------------------------
__global__ __launch_bounds__(256) void k_zero_halo(short* __restrict__ p, int nimg,
                                                   int rs, int ch8) {
    int id = blockIdx.x * 256 + threadIdx.x;
    int njobs = nimg * 260 * ch8;
    if (id >= njobs) return;
    int c8 = id % ch8;
    int rest = id / ch8;
    int px = rest % 260;
    int img = rest / 260;
    int row, col;
    if (px < 66)       { row = 0;  col = px; }
    else if (px < 132) { row = 65; col = px - 66; }
    else { int q = px - 132; row = 1 + (q >> 1); col = (q & 1) ? 65 : 0; }
    short8 z = {0, 0, 0, 0, 0, 0, 0, 0};
    *(short8*)(p + ((size_t)(img * 66 + row) * rs + col) * (ch8 * 8) + c8 * 8) = z;
}

// ---------------------------------------------------------------------------
// Kernel 1: content [B,512,64,64] f32 -> xTc [b][cs8][66][66][64] bf16,
// interior only, pre-swizzled within each 128B pixel-block: slot ^= (colp&7).
// grid 1024 = b(8) x h(64) x half(2); each block handles 2 cb phases.
// ---------------------------------------------------------------------------
__global__ __launch_bounds__(256) void k_transpose(const float* __restrict__ x,
                                                   short* __restrict__ xTc) {
    __shared__ float lds[128][65];
    int blk = blockIdx.x;
    int half = blk & 1;
    int h = (blk >> 1) & 63;
    int b = blk >> 7;
    int t = threadIdx.x;
    for (int q = 0; q < 2; ++q) {
        int cb = half * 2 + q;
        #pragma unroll
        for (int k = 0; k < 32; ++k) {
            int idx = k * 256 + t;
            int c = idx >> 6, w = idx & 63;
            lds[c][w] = x[(((size_t)b * 512 + cb * 128 + c) * 64 + h) * 64 + w];
        }
        __syncthreads();
        #pragma unroll
        for (int k = 0; k < 4; ++k) {
            int j = k * 256 + t;       // 1024 jobs: (w, 16B-slot of 128 ch)
            int w = j >> 4, sl = j & 15;
            int cs = cb * 2 + (sl >> 3);
            int slotp = (sl & 7) ^ ((w + 1) & 7);
            short8 v;
            #pragma unroll
            for (int e = 0; e < 8; ++e) v[e] = f2bf(lds[sl * 8 + e][w]);
            *(short8*)(xTc + (((size_t)(b * 8 + cs) * 66 + (h + 1)) * 66 + (w + 1)) * 64
                           + slotp * 8) = v;
        }
        __syncthreads();
    }
}

// ---------------------------------------------------------------------------
// Kernel 2: Wd_eff fragment-major: wd_frag[b][ci8][kpos9][kt2][mt2][512]
// frag elem = lo*32 + hi*8 + e  (och = mt*16+lo, ch = ci*64+kt*32+hi*8+e)
// ---------------------------------------------------------------------------
__global__ __launch_bounds__(256) void k_fold1(const float* __restrict__ f1,
                                               const float* __restrict__ wd,
                                               short* __restrict__ wd_frag) {
    int id = blockIdx.x * 256 + threadIdx.x;
    int i = id & 511;
    int o = (id >> 9) & 31;
    int b = id >> 14;
    float acc[9];
    #pragma unroll
    for (int k = 0; k < 9; ++k) acc[k] = 0.f;
    for (int m = 0; m < 32; ++m) {
        float f = f1[(b * 32 + o) * 32 + m];
        const float* wrow = wd + ((size_t)m * 512 + i) * 9;
        #pragma unroll
        for (int k = 0; k < 9; ++k) acc[k] += f * wrow[k];
    }
    int ci = i >> 6, kt = (i >> 5) & 1, hi = (i >> 3) & 3, e = i & 7;
    int mt = o >> 4, lo = o & 15;
    #pragma unroll
    for (int k = 0; k < 9; ++k)
        wd_frag[((((size_t)(b * 8 + ci) * 9 + k) * 2 + kt) * 2 + mt) * 512
                + lo * 32 + hi * 8 + e] = f2bf(acc[k]);
}

// ---------------------------------------------------------------------------
// Kernel 3: Wu_eff fragment-major: wu_frag[b][kpos9][g32][512]
// thread = (b, O, c); wu row (288B) dense + wave-uniform; acc over all kpos.
// ---------------------------------------------------------------------------
__global__ __launch_bounds__(256) void k_fold2(const float* __restrict__ f2,
                                               const float* __restrict__ wu,
                                               short* __restrict__ wu_frag) {
    int id = blockIdx.x * 256 + threadIdx.x;   // (b*512+O)*32 + c
    int c = id & 31;
    int O = (id >> 5) & 511;
    int b = id >> 14;
    float acc[9];
    #pragma unroll
    for (int k = 0; k < 9; ++k) acc[k] = 0.f;
    for (int m = 0; m < 32; ++m) {
        float f = f2[(b * 32 + m) * 32 + c];
        const float* wr = wu + ((size_t)O * 32 + m) * 9;
        #pragma unroll
        for (int k = 0; k < 9; ++k) acc[k] += wr[k] * f;
    }
    int g = O >> 4, lo = O & 15, hi = c >> 3, e = c & 7;
    #pragma unroll
    for (int k = 0; k < 9; ++k)
        wu_frag[((size_t)(b * 9 + k) * 32 + g) * 512 + lo * 32 + hi * 8 + e]
            = f2bf(acc[k]);
}

// ---------------------------------------------------------------------------
// Kernel 4: bd_eff[b][o] = sum_m F1[b,o,m] * bd[m]
// ---------------------------------------------------------------------------
__global__ void k_bd(const float* __restrict__ f1, const float* __restrict__ bd,
                     float* __restrict__ bd_eff) {
    int t = threadIdx.x;
    int b = t >> 5, o = t & 31;
    float acc = 0.f;
    #pragma unroll
    for (int m = 0; m < 32; ++m) acc += f1[(b * 32 + o) * 32 + m] * bd[m];
    bd_eff[t] = acc;
}

// ---------------------------------------------------------------------------
// Kernel 5: conv_down FULL-K fused: tp2 = LReLU(conv3x3(x,Wd_eff)+bd_eff).
// block = (b, rows 2rp..2rp+1, col-half cp). grid 512. 8 chunks of 64 ch,
// double-buffered 20KB x-tiles via 20 x gl16(1KB).
// Per chunk: issue ALL 36 A-frag loads FIRST (oldest in vmcnt order), then
// next-chunk staging, then sched_barrier(0) so the A-loads cannot be sunk
// into the MFMA region (round-7 failure: LLVM sank them; VGPR stayed 52
// and the 36 L2 round-trips serialized). Forcing them live batches the
// latency: ~1 round-trip instead of 36.
// wave = (row lr, col-sub chh): 32 och x 16 px, acc[2].
// ---------------------------------------------------------------------------
__global__ __launch_bounds__(256, 2) void k_conv_down(const short* __restrict__ xTc,
                                                      const short* __restrict__ wd_frag,
                                                      const float* __restrict__ bd_eff,
                                                      short* __restrict__ tp2) {
    __shared__ __align__(16) short xs[2][10240];   // 2 x (4*40*64)
    int blk = blockIdx.x;          // 512 = b(8) x rp(32) x cp(2)
    int cp = blk & 1, rp = (blk >> 1) & 31, b = blk >> 6;
    int R0 = rp * 2, W0 = cp * 32;
    int t = threadIdx.x, lane = t & 63, wv = t >> 6;
    int lr = wv >> 1, chh = wv & 1;
    int lo = lane & 15, hi = lane >> 4;

    const char* pb0 = (const char*)xTc + (size_t)(b * 8) * 557568
                    + ((size_t)R0 * 66 + W0) * 128;   // chunk ci adds ci*557568

    // prologue: stage chunk 0
    for (int i = wv; i < 20; i += 4)
        gl16(pb0 + (size_t)(i / 5) * 8448 + (i % 5) * 1024 + lane * 16,
             (char*)&xs[0][0] + i * 1024);            // 8448 = 66*128
    __syncthreads();

    f32x4 acc[2] = {};
    const short* ab0 = wd_frag + (size_t)(b * 8) * 9 * 2 * 2 * 512 + lo * 32 + hi * 8;

    #pragma unroll
    for (int ci = 0; ci < 8; ++ci) {
        // 1) batch-issue ALL A-frag loads for this chunk (must be OLDER than
        //    the staging gl16s so their vmcnt waits don't chain on staging)
        const short* ab = ab0 + (size_t)ci * 18432;    // 9*2*2*512
        short8 areg[9][2][2];
        #pragma unroll
        for (int kp = 0; kp < 9; ++kp)
            #pragma unroll
            for (int kt = 0; kt < 2; ++kt) {
                areg[kp][kt][0] = *(const short8*)(ab + ((kp * 2 + kt) * 2 + 0) * 512);
                areg[kp][kt][1] = *(const short8*)(ab + ((kp * 2 + kt) * 2 + 1) * 512);
            }

        // 2) issue next-chunk staging
        if (ci < 7)
            for (int i = wv; i < 20; i += 4)
                gl16(pb0 + (size_t)(ci + 1) * 557568
                         + (size_t)(i / 5) * 8448 + (i % 5) * 1024 + lane * 16,
                     (char*)&xs[(ci + 1) & 1][0] + i * 1024);

        // 3) pin: nothing (esp. the A-loads) may cross this point
        __builtin_amdgcn_sched_barrier(0);

        const short* xb = &xs[ci & 1][0];
        #pragma unroll
        for (int kh = 0; kh < 3; ++kh) {
            #pragma unroll
            for (int kw = 0; kw < 3; ++kw) {
                const int kpos = kh * 3 + kw;
                #pragma unroll
                for (int kt = 0; kt < 2; ++kt) {
                    int g = chh * 16 + lo + kw;             // tile col 0..33
                    int s = (kt * 4 + hi) ^ (g & 7);
                    short8 bf = *(const short8*)(xb + ((lr + kh) * 40 + g) * 64 + s * 8);
                    acc[0] = __builtin_amdgcn_mfma_f32_16x16x32_bf16(areg[kpos][kt][0], bf, acc[0], 0, 0, 0);
                    acc[1] = __builtin_amdgcn_mfma_f32_16x16x32_bf16(areg[kpos][kt][1], bf, acc[1], 0, 0, 0);
                }
            }
        }
        __syncthreads();
    }

    // epilogue: och = mt*16 + hi*4 + j, px = chh*16 + lo
    int h = R0 + lr, w = W0 + chh * 16 + lo;
    int colp = w + 1;
    short* ob = tp2 + ((size_t)(b * 66 + h + 1) * 80 + colp) * 32;
    #pragma unroll
    for (int mt = 0; mt < 2; ++mt) {
        f32x4 bd4 = *(const f32x4*)(bd_eff + b * 32 + mt * 16 + hi * 4);
        short4v sv;
        #pragma unroll
        for (int j = 0; j < 4; ++j) {
            float f = acc[mt][j] + bd4[j];
            f = f > 0.f ? f : 0.2f * f;
            sv[j] = f2bf(f);
        }
        int sl = mt * 2 + (hi >> 1);
        int slp = sl ^ (colp & 3);
        *(short4v*)(ob + slp * 8 + (hi & 1) * 4) = sv;
    }
}

// ---------------------------------------------------------------------------
// Kernel 6: conv_up + residual.  block = (b, 2 rows, 128 och). grid 1024.
// t-tile 4 rows x 80 x 32 = 20 KiB staged once (20 x gl16), 1 barrier,
// then straight-line 9-kpos compute with 1-deep A-frag software pipeline.
// wave = 64 och x 64 px: 4mt x 4nt.
// ---------------------------------------------------------------------------
__global__ __launch_bounds__(256, 4) void k_conv_up(const short* __restrict__ tp2,
                                                    const short* __restrict__ wu_frag,
                                                    const float* __restrict__ content,
                                                    const float* __restrict__ bu,
                                                    float* __restrict__ out) {
    __shared__ __align__(16) short tl[10240];   // 4 x 80 x 32
    int blk = blockIdx.x;      // 1024 = b(8) x hb(32) x ocq(4)
    int ocq = blk & 3, hb = (blk >> 2) & 31, b = blk >> 7;
    int t = threadIdx.x, lane = t & 63, wv = t >> 6;
    int lr = wv >> 1, oh = wv & 1;
    int lo = lane & 15, hi = lane >> 4;
    int Ob = ocq * 128 + oh * 64;
    int R0 = 2 * hb;

    const char* sbase = (const char*)tp2 + ((size_t)(b * 66 + R0) * 80) * 64;
    for (int i = wv; i < 20; i += 4)
        gl16(sbase + i * 1024 + lane * 16, (char*)tl + i * 1024);

    const short* ab0 = wu_frag + ((size_t)(b * 9) * 32 + (Ob >> 4)) * 512
                     + lo * 32 + hi * 8;

    // preload kpos 0 A-frags while the gl16s are in flight
    short8 a_pre[4];
    #pragma unroll
    for (int mt = 0; mt < 4; ++mt)
        a_pre[mt] = *(const short8*)(ab0 + (size_t)mt * 512);

    __syncthreads();

    f32x4 acc[4][4] = {};

    #pragma unroll
    for (int kh = 0; kh < 3; ++kh) {
        #pragma unroll
        for (int kw = 0; kw < 3; ++kw) {
            const int kpos = kh * 3 + kw;
            short8 a_use[4];
            #pragma unroll
            for (int mt = 0; mt < 4; ++mt) a_use[mt] = a_pre[mt];
            if (kpos < 8) {
                #pragma unroll
                for (int mt = 0; mt < 4; ++mt)
                    a_pre[mt] = *(const short8*)(ab0 + ((size_t)(kpos + 1) * 32 + mt) * 512);
            }
            short8 bf0, bf1, bf2, bf3;
            #pragma unroll
            for (int nt = 0; nt < 4; ++nt) {
                int g = nt * 16 + lo + kw;                 // padded col 0..65
                short8 bf = *(const short8*)(tl + ((lr + kh) * 80 + g) * 32
                                                + ((hi ^ (g & 3)) << 3));
                if (nt == 0) bf0 = bf; else if (nt == 1) bf1 = bf;
                else if (nt == 2) bf2 = bf; else bf3 = bf;
            }
            #pragma unroll
            for (int mt = 0; mt < 4; ++mt) {
                acc[mt][0] = __builtin_amdgcn_mfma_f32_16x16x32_bf16(a_use[mt], bf0, acc[mt][0], 0, 0, 0);
                acc[mt][1] = __builtin_amdgcn_mfma_f32_16x16x32_bf16(a_use[mt], bf1, acc[mt][1], 0, 0, 0);
                acc[mt][2] = __builtin_amdgcn_mfma_f32_16x16x32_bf16(a_use[mt], bf2, acc[mt][2], 0, 0, 0);
                acc[mt][3] = __builtin_amdgcn_mfma_f32_16x16x32_bf16(a_use[mt], bf3, acc[mt][3], 0, 0, 0);
            }
        }
    }

    int h = R0 + lr;
    #pragma unroll
    for (int mt = 0; mt < 4; ++mt) {
        f32x4 bu4 = *(const f32x4*)(bu + Ob + mt * 16 + hi * 4);
        #pragma unroll
        for (int nt = 0; nt < 4; ++nt) {
            int px = nt * 16 + lo;
            #pragma unroll
            for (int j = 0; j < 4; ++j) {
                int O = Ob + mt * 16 + hi * 4 + j;
                size_t gidx = (((size_t)(b * 512 + O) * 64) + h) * 64 + px;
                out[gidx] = acc[mt][nt][j] + content[gidx] + bu4[j];
            }
        }
    }
}

// ---------------------------------------------------------------------------
extern "C" void kernel_launch(void* const* d_in, const int* in_sizes, int n_in,
                              void* d_out, int out_size, void* d_ws, size_t ws_size,
                              hipStream_t stream) {
    const float* content = (const float*)d_in[0];
    const float* f1      = (const float*)d_in[1];
    const float* f2      = (const float*)d_in[2];
    const float* wd      = (const float*)d_in[3];
    const float* bd      = (const float*)d_in[4];
    const float* wu      = (const float*)d_in[5];
    const float* bu      = (const float*)d_in[6];
    float* out = (float*)d_out;

    char* ws = (char*)d_ws;
    // layout (bytes):
    //   xTc    [8][8][66][66][64] bf16 : 35,684,352
    //   wd_frag                        :  2,359,296
    //   wu_frag                        :  2,359,296
    //   bd_eff                         :      1,024
    //   tp2    [8][66][80][32] bf16    :  2,703,360   (total ~43.1 MiB)
    short* xTc     = (short*)(ws);
    short* wd_frag = (short*)(ws + 35684352);
    short* wu_frag = (short*)(ws + 38043648);
    float* bd_eff  = (float*)(ws + 40402944);
    short* tp2     = (short*)(ws + 40403968);

    k_zero_halo<<<dim3(520),  dim3(256), 0, stream>>>(xTc, 64, 66, 8);
    k_zero_halo<<<dim3(33),   dim3(256), 0, stream>>>(tp2, 8, 80, 4);
    k_transpose<<<dim3(1024), dim3(256), 0, stream>>>(content, xTc);
    k_fold1    <<<dim3(512),  dim3(256), 0, stream>>>(f1, wd, wd_frag);
    k_fold2    <<<dim3(512),  dim3(256), 0, stream>>>(f2, wu, wu_frag);
    k_bd       <<<dim3(1),    dim3(256), 0, stream>>>(f1, bd, bd_eff);
    k_conv_down<<<dim3(512),  dim3(256), 0, stream>>>(xTc, wd_frag, bd_eff, tp2);
    k_conv_up  <<<dim3(1024), dim3(256), 0, stream>>>(tp2, wu_frag, content, bu, out);
}

// Round 9
// 102.421 us; speedup vs baseline: 1.1361x; 1.1361x over previous
//
#include <hip/hip_runtime.h>
#include <hip/hip_bf16.h>

typedef __attribute__((ext_vector_type(8)))  short short8;
typedef __attribute__((ext_vector_type(4)))  short short4v;
typedef __attribute__((ext_vector_type(4)))  float f32x4;

static __device__ inline short f2bf(float f) {
    union { __hip_bfloat16 h; unsigned short u; } cv;
    cv.h = __float2bfloat16(f);
    return (short)cv.u;
}

typedef __attribute__((address_space(3))) void lds_void;
typedef const __attribute__((address_space(1))) void glob_void;
static __device__ inline void gl16(const void* g, void* l) {
    // global -> LDS direct copy, 16 B/lane (1 KiB/wave). LDS dest must be
    // wave-uniform base (+ lane*16 HW-added); global src is per-lane.
    __builtin_amdgcn_global_load_lds((glob_void*)g, (lds_void*)l, 16, 0, 0);
}

// ---------------------------------------------------------------------------
// Kernel 0: zero halo of padded [nimg][66][rs][ch8*8] bf16 buffer (cols 0..65).
// ---------------------------------------------------------------------------
__global__ __launch_bounds__(256) void k_zero_halo(short* __restrict__ p, int nimg,
                                                   int rs, int ch8) {
    int id = blockIdx.x * 256 + threadIdx.x;
    int njobs = nimg * 260 * ch8;
    if (id >= njobs) return;
    int c8 = id % ch8;
    int rest = id / ch8;
    int px = rest % 260;
    int img = rest / 260;
    int row, col;
    if (px < 66)       { row = 0;  col = px; }
    else if (px < 132) { row = 65; col = px - 66; }
    else { int q = px - 132; row = 1 + (q >> 1); col = (q & 1) ? 65 : 0; }
    short8 z = {0, 0, 0, 0, 0, 0, 0, 0};
    *(short8*)(p + ((size_t)(img * 66 + row) * rs + col) * (ch8 * 8) + c8 * 8) = z;
}

// ---------------------------------------------------------------------------
// Kernel 1: content [B,512,64,64] f32 -> xTc [b][cs8][66][66][64] bf16,
// interior only, pre-swizzled within each 128B pixel-block: slot ^= (colp&7).
// Loads vectorized f32x4; LDS bounce scalar stores (HBM-bound kernel).
// ---------------------------------------------------------------------------
__global__ __launch_bounds__(256) void k_transpose(const float* __restrict__ x,
                                                   short* __restrict__ xTc) {
    __shared__ float lds[128][65];
    int blk = blockIdx.x;
    int half = blk & 1;
    int h = (blk >> 1) & 63;
    int b = blk >> 7;
    int t = threadIdx.x;
    for (int q = 0; q < 2; ++q) {
        int cb = half * 2 + q;
        #pragma unroll
        for (int k = 0; k < 8; ++k) {
            int idx = k * 256 + t;          // 2048 jobs: (c, 4-float group)
            int c = idx >> 4, wq = idx & 15;
            f32x4 v = *(const f32x4*)(x + (((size_t)b * 512 + cb * 128 + c) * 64 + h) * 64
                                        + wq * 4);
            lds[c][wq * 4 + 0] = v.x;
            lds[c][wq * 4 + 1] = v.y;
            lds[c][wq * 4 + 2] = v.z;
            lds[c][wq * 4 + 3] = v.w;
        }
        __syncthreads();
        #pragma unroll
        for (int k = 0; k < 4; ++k) {
            int j = k * 256 + t;       // 1024 jobs: (w, 16B-slot of 128 ch)
            int w = j >> 4, sl = j & 15;
            int cs = cb * 2 + (sl >> 3);
            int slotp = (sl & 7) ^ ((w + 1) & 7);
            short8 v;
            #pragma unroll
            for (int e = 0; e < 8; ++e) v[e] = f2bf(lds[sl * 8 + e][w]);
            *(short8*)(xTc + (((size_t)(b * 8 + cs) * 66 + (h + 1)) * 66 + (w + 1)) * 64
                           + slotp * 8) = v;
        }
        __syncthreads();
    }
}

// ---------------------------------------------------------------------------
// Kernel 2: Wd_eff fragment-major, chunk=32ch, LANE-LINEAR frags:
// wd_frag[b][ci16][kpos9][mt2][512]; elem (hi*16+lo)*8+e holds
// Wd_eff[och=mt*16+lo][ch=ci*32+hi*8+e]  -> gl16-stageable + conflict-free.
// ---------------------------------------------------------------------------
__global__ __launch_bounds__(256) void k_fold1(const float* __restrict__ f1,
                                               const float* __restrict__ wd,
                                               short* __restrict__ wd_frag) {
    int id = blockIdx.x * 256 + threadIdx.x;
    int i = id & 511;
    int o = (id >> 9) & 31;
    int b = id >> 14;
    float acc[9];
    #pragma unroll
    for (int k = 0; k < 9; ++k) acc[k] = 0.f;
    for (int m = 0; m < 32; ++m) {
        float f = f1[(b * 32 + o) * 32 + m];
        const float* wrow = wd + ((size_t)m * 512 + i) * 9;
        #pragma unroll
        for (int k = 0; k < 9; ++k) acc[k] += f * wrow[k];
    }
    int ci = i >> 5, hi = (i >> 3) & 3, e = i & 7;
    int mt = o >> 4, lo = o & 15;
    #pragma unroll
    for (int k = 0; k < 9; ++k)
        wd_frag[(((size_t)(b * 16 + ci) * 9 + k) * 2 + mt) * 512
                + hi * 128 + lo * 8 + e] = f2bf(acc[k]);
}

// ---------------------------------------------------------------------------
// Kernel 3: Wu_eff fragment-major: wu_frag[b][kpos9][g32][512]
// thread = (b, O, c); wu row (288B) dense + wave-uniform; acc over all kpos.
// ---------------------------------------------------------------------------
__global__ __launch_bounds__(256) void k_fold2(const float* __restrict__ f2,
                                               const float* __restrict__ wu,
                                               short* __restrict__ wu_frag) {
    int id = blockIdx.x * 256 + threadIdx.x;   // (b*512+O)*32 + c
    int c = id & 31;
    int O = (id >> 5) & 511;
    int b = id >> 14;
    float acc[9];
    #pragma unroll
    for (int k = 0; k < 9; ++k) acc[k] = 0.f;
    for (int m = 0; m < 32; ++m) {
        float f = f2[(b * 32 + m) * 32 + c];
        const float* wr = wu + ((size_t)O * 32 + m) * 9;
        #pragma unroll
        for (int k = 0; k < 9; ++k) acc[k] += wr[k] * f;
    }
    int g = O >> 4, lo = O & 15, hi = c >> 3, e = c & 7;
    #pragma unroll
    for (int k = 0; k < 9; ++k)
        wu_frag[((size_t)(b * 9 + k) * 32 + g) * 512 + lo * 32 + hi * 8 + e]
            = f2bf(acc[k]);
}

// ---------------------------------------------------------------------------
// Kernel 4: bd_eff[b][o] = sum_m F1[b,o,m] * bd[m]
// ---------------------------------------------------------------------------
__global__ void k_bd(const float* __restrict__ f1, const float* __restrict__ bd,
                     float* __restrict__ bd_eff) {
    int t = threadIdx.x;
    int b = t >> 5, o = t & 31;
    float acc = 0.f;
    #pragma unroll
    for (int m = 0; m < 32; ++m) acc += f1[(b * 32 + o) * 32 + m] * bd[m];
    bd_eff[t] = acc;
}

// ---------------------------------------------------------------------------
// Kernel 5: conv_down, fully-piped: tp2 = LReLU(conv3x3(x,Wd_eff)+bd).
// block = (b, 2 rows, 32-col half), 2 waves; wave = 32och x 32px (2mt x 2nt).
// 16 chunks of 32ch. BOTH operands staged via gl16 (A-serialization was the
// round 6-8 wall: convoyed waves issuing identical global A-addresses =
// one serial L2 stream/CU). Per chunk: 15 gl16/wave (x 12 jobs de-swizzled
// via per-lane src, A 18 jobs lane-linear), counted s_waitcnt vmcnt(15) +
// raw s_barrier (never vmcnt(0) in-loop). LDS 2x30KB. XCD swizzle: batch<->XCD.
// ---------------------------------------------------------------------------
__global__ __launch_bounds__(128) void k_conv_down(const char* __restrict__ xTc,
                                                   const char* __restrict__ wd_frag,
                                                   const float* __restrict__ bd_eff,
                                                   short* __restrict__ tp2) {
    __shared__ __align__(16) char xs[2][12288];   // [4 rows][48 cols][64 B]
    __shared__ __align__(16) char as_[2][18432];  // [9 kpos][2 mt][1 KB frag]
    int d = blockIdx.x;                // 512
    int nb = (d & 7) * 64 + (d >> 3);  // XCD x <-> batch x
    int b = nb >> 6, rp = (nb >> 1) & 31, cp = nb & 1;
    int R0 = rp * 2, W0 = cp * 32;
    int t = threadIdx.x, lane = t & 63, wv = t >> 6;   // wv 0..1
    int lo = lane & 15, hi = lane >> 4;
    int pxl = lane >> 2, s4 = lane & 3;

    const char* wdb = wd_frag + (size_t)(b * 16) * 18432;
    const char* xbb = xTc + (size_t)(b * 8) * 557568;

#define STAGE_CD(ci, bf)                                                         \
    {                                                                            \
        const int ci_ = (ci);                                                    \
        const char* xpl = xbb + (size_t)(ci_ >> 1) * 557568;                     \
        const char* apl = wdb + (size_t)ci_ * 18432;                             \
        int half4 = (ci_ & 1) * 4;                                               \
        _Pragma("unroll")                                                        \
        for (int i2 = 0; i2 < 15; ++i2) {                                        \
            int j = wv * 15 + i2;                                                \
            if (j < 12) {                                                        \
                int col = W0 + (j % 3) * 16 + pxl;                               \
                gl16(xpl + ((size_t)((R0 + j / 3) * 66 + col)) * 128             \
                         + (((half4 + s4) ^ (col & 7)) << 4),                    \
                     xs[bf] + j * 1024);                                         \
            } else {                                                             \
                gl16(apl + (j - 12) * 1024 + lane * 16,                          \
                     as_[bf] + (j - 12) * 1024);                                 \
            }                                                                    \
        }                                                                        \
    }

    f32x4 acc[2][2] = {};

    STAGE_CD(0, 0);

    #pragma unroll 2
    for (int ci = 0; ci < 16; ++ci) {
        int bf = ci & 1;
        STAGE_CD((ci + 1) & 15, bf ^ 1);
        asm volatile("s_waitcnt vmcnt(15)" ::: "memory");
        __builtin_amdgcn_sched_barrier(0);
        __builtin_amdgcn_s_barrier();
        __builtin_amdgcn_sched_barrier(0);

        const char* xb = xs[bf];
        const char* ab = as_[bf];
        #pragma unroll
        for (int kh = 0; kh < 3; ++kh) {
            #pragma unroll
            for (int kw = 0; kw < 3; ++kw) {
                const int kpos = kh * 3 + kw;
                short8 a0 = *(const short8*)(ab + (kpos * 2 + 0) * 1024 + lane * 16);
                short8 a1 = *(const short8*)(ab + (kpos * 2 + 1) * 1024 + lane * 16);
                short8 b0 = *(const short8*)(xb + ((wv + kh) * 48 + lo + kw) * 64
                                                + hi * 16);
                short8 b1 = *(const short8*)(xb + ((wv + kh) * 48 + 16 + lo + kw) * 64
                                                + hi * 16);
                acc[0][0] = __builtin_amdgcn_mfma_f32_16x16x32_bf16(a0, b0, acc[0][0], 0, 0, 0);
                acc[0][1] = __builtin_amdgcn_mfma_f32_16x16x32_bf16(a0, b1, acc[0][1], 0, 0, 0);
                acc[1][0] = __builtin_amdgcn_mfma_f32_16x16x32_bf16(a1, b0, acc[1][0], 0, 0, 0);
                acc[1][1] = __builtin_amdgcn_mfma_f32_16x16x32_bf16(a1, b1, acc[1][1], 0, 0, 0);
            }
        }
        __builtin_amdgcn_sched_barrier(0);
        __builtin_amdgcn_s_barrier();
    }
#undef STAGE_CD

    // epilogue: och = mt*16 + hi*4 + j, px col = W0 + nt*16 + lo, row = R0+wv
    int h = R0 + wv;
    #pragma unroll
    for (int nt = 0; nt < 2; ++nt) {
        int colp = W0 + nt * 16 + lo + 1;
        short* ob = tp2 + ((size_t)(b * 66 + h + 1) * 80 + colp) * 32;
        #pragma unroll
        for (int mt = 0; mt < 2; ++mt) {
            f32x4 bd4 = *(const f32x4*)(bd_eff + b * 32 + mt * 16 + hi * 4);
            short4v sv;
            #pragma unroll
            for (int j = 0; j < 4; ++j) {
                float f = acc[mt][nt][j] + bd4[j];
                f = f > 0.f ? f : 0.2f * f;
                sv[j] = f2bf(f);
            }
            int sl = mt * 2 + (hi >> 1);
            int slp = sl ^ (colp & 3);
            *(short4v*)(ob + slp * 8 + (hi & 1) * 4) = sv;
        }
    }
}

// ---------------------------------------------------------------------------
// Kernel 6: conv_up + residual.  block = (b, 2 rows, 128 och). grid 1024.
// t-tile 4 rows x 80 x 32 = 20 KiB staged once (20 x gl16), 1 barrier,
// straight-line 9-kpos compute + 1-deep A prefetch. XCD swizzle: batch<->XCD
// so wu_frag (294 KB/b) and tp2 (337 KB/b) are L2-resident per XCD.
// ---------------------------------------------------------------------------
__global__ __launch_bounds__(256, 3) void k_conv_up(const short* __restrict__ tp2,
                                                    const short* __restrict__ wu_frag,
                                                    const float* __restrict__ content,
                                                    const float* __restrict__ bu,
                                                    float* __restrict__ out) {
    __shared__ __align__(16) short tl[10240];   // 4 x 80 x 32
    int d = blockIdx.x;                 // 1024
    int nb = (d & 7) * 128 + (d >> 3);  // XCD x <-> batch x
    int ocq = nb & 3, hb = (nb >> 2) & 31, b = nb >> 7;
    int t = threadIdx.x, lane = t & 63, wv = t >> 6;
    int lr = wv >> 1, oh = wv & 1;
    int lo = lane & 15, hi = lane >> 4;
    int Ob = ocq * 128 + oh * 64;
    int R0 = 2 * hb;

    const char* sbase = (const char*)tp2 + ((size_t)(b * 66 + R0) * 80) * 64;
    for (int i = wv; i < 20; i += 4)
        gl16(sbase + i * 1024 + lane * 16, (char*)tl + i * 1024);

    const short* ab0 = wu_frag + ((size_t)(b * 9) * 32 + (Ob >> 4)) * 512
                     + lo * 32 + hi * 8;

    // preload kpos 0 A-frags while the gl16s are in flight
    short8 a_pre[4];
    #pragma unroll
    for (int mt = 0; mt < 4; ++mt)
        a_pre[mt] = *(const short8*)(ab0 + (size_t)mt * 512);

    __syncthreads();

    f32x4 acc[4][4] = {};

    #pragma unroll
    for (int kh = 0; kh < 3; ++kh) {
        #pragma unroll
        for (int kw = 0; kw < 3; ++kw) {
            const int kpos = kh * 3 + kw;
            short8 a_use[4];
            #pragma unroll
            for (int mt = 0; mt < 4; ++mt) a_use[mt] = a_pre[mt];
            if (kpos < 8) {
                #pragma unroll
                for (int mt = 0; mt < 4; ++mt)
                    a_pre[mt] = *(const short8*)(ab0 + ((size_t)(kpos + 1) * 32 + mt) * 512);
            }
            short8 bf0, bf1, bf2, bf3;
            #pragma unroll
            for (int nt = 0; nt < 4; ++nt) {
                int g = nt * 16 + lo + kw;                 // padded col 0..65
                short8 bf = *(const short8*)(tl + ((lr + kh) * 80 + g) * 32
                                                + ((hi ^ (g & 3)) << 3));
                if (nt == 0) bf0 = bf; else if (nt == 1) bf1 = bf;
                else if (nt == 2) bf2 = bf; else bf3 = bf;
            }
            #pragma unroll
            for (int mt = 0; mt < 4; ++mt) {
                acc[mt][0] = __builtin_amdgcn_mfma_f32_16x16x32_bf16(a_use[mt], bf0, acc[mt][0], 0, 0, 0);
                acc[mt][1] = __builtin_amdgcn_mfma_f32_16x16x32_bf16(a_use[mt], bf1, acc[mt][1], 0, 0, 0);
                acc[mt][2] = __builtin_amdgcn_mfma_f32_16x16x32_bf16(a_use[mt], bf2, acc[mt][2], 0, 0, 0);
                acc[mt][3] = __builtin_amdgcn_mfma_f32_16x16x32_bf16(a_use[mt], bf3, acc[mt][3], 0, 0, 0);
            }
        }
    }

    int h = R0 + lr;
    #pragma unroll
    for (int mt = 0; mt < 4; ++mt) {
        f32x4 bu4 = *(const f32x4*)(bu + Ob + mt * 16 + hi * 4);
        #pragma unroll
        for (int nt = 0; nt < 4; ++nt) {
            int px = nt * 16 + lo;
            #pragma unroll
            for (int j = 0; j < 4; ++j) {
                int O = Ob + mt * 16 + hi * 4 + j;
                size_t gidx = (((size_t)(b * 512 + O) * 64) + h) * 64 + px;
                out[gidx] = acc[mt][nt][j] + content[gidx] + bu4[j];
            }
        }
    }
}

// ---------------------------------------------------------------------------
extern "C" void kernel_launch(void* const* d_in, const int* in_sizes, int n_in,
                              void* d_out, int out_size, void* d_ws, size_t ws_size,
                              hipStream_t stream) {
    const float* content = (const float*)d_in[0];
    const float* f1      = (const float*)d_in[1];
    const float* f2      = (const float*)d_in[2];
    const float* wd      = (const float*)d_in[3];
    const float* bd      = (const float*)d_in[4];
    const float* wu      = (const float*)d_in[5];
    const float* bu      = (const float*)d_in[6];
    float* out = (float*)d_out;

    char* ws = (char*)d_ws;
    // layout (bytes):
    //   xTc    [8][8][66][66][64] bf16 : 35,684,352
    //   wd_frag                        :  2,359,296
    //   wu_frag                        :  2,359,296
    //   bd_eff                         :      1,024
    //   tp2    [8][66][80][32] bf16    :  2,703,360   (total ~43.1 MiB)
    short* xTc     = (short*)(ws);
    short* wd_frag = (short*)(ws + 35684352);
    short* wu_frag = (short*)(ws + 38043648);
    float* bd_eff  = (float*)(ws + 40402944);
    short* tp2     = (short*)(ws + 40403968);

    k_zero_halo<<<dim3(520),  dim3(256), 0, stream>>>(xTc, 64, 66, 8);
    k_zero_halo<<<dim3(33),   dim3(256), 0, stream>>>(tp2, 8, 80, 4);
    k_transpose<<<dim3(1024), dim3(256), 0, stream>>>(content, xTc);
    k_fold1    <<<dim3(512),  dim3(256), 0, stream>>>(f1, wd, wd_frag);
    k_fold2    <<<dim3(512),  dim3(256), 0, stream>>>(f2, wu, wu_frag);
    k_bd       <<<dim3(1),    dim3(256), 0, stream>>>(f1, bd, bd_eff);
    k_conv_down<<<dim3(512),  dim3(128), 0, stream>>>((const char*)xTc,
                                                      (const char*)wd_frag,
                                                      bd_eff, tp2);
    k_conv_up  <<<dim3(1024), dim3(256), 0, stream>>>(tp2, wu_frag, content, bu, out);
}

// Round 10
// 94.248 us; speedup vs baseline: 1.2346x; 1.0867x over previous
//
#include <hip/hip_runtime.h>
#include <hip/hip_bf16.h>

typedef __attribute__((ext_vector_type(8)))  short short8;
typedef __attribute__((ext_vector_type(4)))  short short4v;
typedef __attribute__((ext_vector_type(4)))  float f32x4;

static __device__ inline short f2bf(float f) {
    union { __hip_bfloat16 h; unsigned short u; } cv;
    cv.h = __float2bfloat16(f);
    return (short)cv.u;
}

typedef __attribute__((address_space(3))) void lds_void;
typedef const __attribute__((address_space(1))) void glob_void;
static __device__ inline void gl16(const void* g, void* l) {
    // global -> LDS direct copy, 16 B/lane (1 KiB/wave). LDS dest must be
    // wave-uniform base (+ lane*16 HW-added); global src is per-lane.
    __builtin_amdgcn_global_load_lds((glob_void*)g, (lds_void*)l, 16, 0, 0);
}

// ---------------------------------------------------------------------------
// Kernel 0: zero halo of padded [nimg][66][rs][ch8*8] bf16 buffer (cols 0..65).
// ---------------------------------------------------------------------------
__global__ __launch_bounds__(256) void k_zero_halo(short* __restrict__ p, int nimg,
                                                   int rs, int ch8) {
    int id = blockIdx.x * 256 + threadIdx.x;
    int njobs = nimg * 260 * ch8;
    if (id >= njobs) return;
    int c8 = id % ch8;
    int rest = id / ch8;
    int px = rest % 260;
    int img = rest / 260;
    int row, col;
    if (px < 66)       { row = 0;  col = px; }
    else if (px < 132) { row = 65; col = px - 66; }
    else { int q = px - 132; row = 1 + (q >> 1); col = (q & 1) ? 65 : 0; }
    short8 z = {0, 0, 0, 0, 0, 0, 0, 0};
    *(short8*)(p + ((size_t)(img * 66 + row) * rs + col) * (ch8 * 8) + c8 * 8) = z;
}

// ---------------------------------------------------------------------------
// Kernel 1: content [B,512,64,64] f32 -> xTc [b][cs8][66][66][64] bf16,
// interior only, pre-swizzled within each 128B pixel-block: slot ^= (colp&7).
// ---------------------------------------------------------------------------
__global__ __launch_bounds__(256) void k_transpose(const float* __restrict__ x,
                                                   short* __restrict__ xTc) {
    __shared__ float lds[128][65];
    int blk = blockIdx.x;
    int half = blk & 1;
    int h = (blk >> 1) & 63;
    int b = blk >> 7;
    int t = threadIdx.x;
    for (int q = 0; q < 2; ++q) {
        int cb = half * 2 + q;
        #pragma unroll
        for (int k = 0; k < 8; ++k) {
            int idx = k * 256 + t;          // 2048 jobs: (c, 4-float group)
            int c = idx >> 4, wq = idx & 15;
            f32x4 v = *(const f32x4*)(x + (((size_t)b * 512 + cb * 128 + c) * 64 + h) * 64
                                        + wq * 4);
            lds[c][wq * 4 + 0] = v.x;
            lds[c][wq * 4 + 1] = v.y;
            lds[c][wq * 4 + 2] = v.z;
            lds[c][wq * 4 + 3] = v.w;
        }
        __syncthreads();
        #pragma unroll
        for (int k = 0; k < 4; ++k) {
            int j = k * 256 + t;       // 1024 jobs: (w, 16B-slot of 128 ch)
            int w = j >> 4, sl = j & 15;
            int cs = cb * 2 + (sl >> 3);
            int slotp = (sl & 7) ^ ((w + 1) & 7);
            short8 v;
            #pragma unroll
            for (int e = 0; e < 8; ++e) v[e] = f2bf(lds[sl * 8 + e][w]);
            *(short8*)(xTc + (((size_t)(b * 8 + cs) * 66 + (h + 1)) * 66 + (w + 1)) * 64
                           + slotp * 8) = v;
        }
        __syncthreads();
    }
}

// ---------------------------------------------------------------------------
// Kernel 2: Wd_eff fragment-major, chunk=32ch, LANE-LINEAR frags:
// wd_frag[b][ci16][kpos9][mt2][512]; elem (hi*16+lo)*8+e holds
// Wd_eff[och=mt*16+lo][ch=ci*32+hi*8+e]  -> gl16-stageable + conflict-free.
// ---------------------------------------------------------------------------
__global__ __launch_bounds__(256) void k_fold1(const float* __restrict__ f1,
                                               const float* __restrict__ wd,
                                               short* __restrict__ wd_frag) {
    int id = blockIdx.x * 256 + threadIdx.x;
    int i = id & 511;
    int o = (id >> 9) & 31;
    int b = id >> 14;
    float acc[9];
    #pragma unroll
    for (int k = 0; k < 9; ++k) acc[k] = 0.f;
    for (int m = 0; m < 32; ++m) {
        float f = f1[(b * 32 + o) * 32 + m];
        const float* wrow = wd + ((size_t)m * 512 + i) * 9;
        #pragma unroll
        for (int k = 0; k < 9; ++k) acc[k] += f * wrow[k];
    }
    int ci = i >> 5, hi = (i >> 3) & 3, e = i & 7;
    int mt = o >> 4, lo = o & 15;
    #pragma unroll
    for (int k = 0; k < 9; ++k)
        wd_frag[(((size_t)(b * 16 + ci) * 9 + k) * 2 + mt) * 512
                + hi * 128 + lo * 8 + e] = f2bf(acc[k]);
}

// ---------------------------------------------------------------------------
// Kernel 3: Wu_eff fragment-major: wu_frag[b][kpos9][g32][512]
// thread = (b, O, c); wu row (288B) dense + wave-uniform; acc over all kpos.
// ---------------------------------------------------------------------------
__global__ __launch_bounds__(256) void k_fold2(const float* __restrict__ f2,
                                               const float* __restrict__ wu,
                                               short* __restrict__ wu_frag) {
    int id = blockIdx.x * 256 + threadIdx.x;   // (b*512+O)*32 + c
    int c = id & 31;
    int O = (id >> 5) & 511;
    int b = id >> 14;
    float acc[9];
    #pragma unroll
    for (int k = 0; k < 9; ++k) acc[k] = 0.f;
    for (int m = 0; m < 32; ++m) {
        float f = f2[(b * 32 + m) * 32 + c];
        const float* wr = wu + ((size_t)O * 32 + m) * 9;
        #pragma unroll
        for (int k = 0; k < 9; ++k) acc[k] += wr[k] * f;
    }
    int g = O >> 4, lo = O & 15, hi = c >> 3, e = c & 7;
    #pragma unroll
    for (int k = 0; k < 9; ++k)
        wu_frag[((size_t)(b * 9 + k) * 32 + g) * 512 + lo * 32 + hi * 8 + e]
            = f2bf(acc[k]);
}

// ---------------------------------------------------------------------------
// Kernel 4: bd_eff[b][o] = sum_m F1[b,o,m] * bd[m]
// ---------------------------------------------------------------------------
__global__ void k_bd(const float* __restrict__ f1, const float* __restrict__ bd,
                     float* __restrict__ bd_eff) {
    int t = threadIdx.x;
    int b = t >> 5, o = t & 31;
    float acc = 0.f;
    #pragma unroll
    for (int m = 0; m < 32; ++m) acc += f1[(b * 32 + o) * 32 + m] * bd[m];
    bd_eff[t] = acc;
}

// ---------------------------------------------------------------------------
// Kernel 5: conv_down, K-split pipelined: tp2 = LReLU(conv3x3(x,Wd)+bd).
// block = (b, 2 rows, full 64 cols), 8 waves (512 thr):
// wave = (ks: K-half, lr: row, colh: col-half), tile 32och x 32px, acc[2][2].
// ks=0 -> chunks 0-7, ks=1 -> chunks 8-15: 8 pipelined iterations; final
// cross-wave pair reduce via LDS scratch (no global partials).
// Per iter: 72 gl16 jobs (x 2x17 w/ overlap-tail, A 2x18, 2 dups) = 9/wave,
// counted s_waitcnt vmcnt(9); last iter peeled with vmcnt(0) (scratch reuse).
// LDS 138KB (2ks x 2buf x (16.9K x + 18K A)) -> 1 block/CU, 2 waves/SIMD
// (R9 ran 1 wave/SIMD: zero TLP at every vmcnt/barrier edge = ~30us).
// x read swizzle: phys slot = hi ^ ((col>>1)&3) within 64B: exactly 2
// lanes/bank-quad = conflict-free; inverse applied on global src (rule #21).
// ---------------------------------------------------------------------------
__global__ __launch_bounds__(512) void k_conv_down(const char* __restrict__ xTc,
                                                   const char* __restrict__ wd_frag,
                                                   const float* __restrict__ bd_eff,
                                                   short* __restrict__ tp2) {
    __shared__ __align__(16) char xs[2][2][16896];   // [ks][buf][4r x 66c x 64B]
    __shared__ __align__(16) char as_[2][2][18432];  // [ks][buf][9 kpos][2 mt][1KB]
    int d = blockIdx.x;                // 256
    int nb = (d & 7) * 32 + (d >> 3);  // XCD <-> batch swizzle
    int b = nb >> 5, rp = nb & 31;
    int R0 = rp * 2;
    int t = threadIdx.x, lane = t & 63, wv = t >> 6;   // wv 0..7
    int ks = wv >> 2, lr = (wv >> 1) & 1, colh = wv & 1;
    int lo = lane & 15, hi = lane >> 4;

    const char* wdb = wd_frag + (size_t)(b * 16) * 18432;
    const char* xbb = xTc + (size_t)(b * 8) * 557568;

#define STAGE_CD(ci, bf)                                                         \
    {                                                                            \
        const int cc0 = (ci);                                                    \
        const int half4 = (cc0 & 1) * 4;                                         \
        const char* xpl0 = xbb + (size_t)(cc0 >> 1) * 557568;                    \
        const char* xpl1 = xpl0 + (size_t)4 * 557568;                            \
        const char* apl0 = wdb + (size_t)cc0 * 18432;                            \
        const char* apl1 = apl0 + (size_t)8 * 18432;                             \
        _Pragma("unroll")                                                        \
        for (int i2 = 0; i2 < 9; ++i2) {                                         \
            int j = wv * 9 + i2;                                                 \
            if (j >= 70) j -= 70;                                                \
            if (j < 34) {                       /* x job */                      \
                int kss = (j >= 17);                                             \
                int jj = kss ? j - 17 : j;                                       \
                int off = (jj < 16) ? jj * 1024 : 15872;                         \
                int dd = off + (lane << 4);                                      \
                int r = dd / 4224;                                               \
                int rem = dd - r * 4224;                                         \
                int col = rem >> 6;                                              \
                int s4 = (rem >> 4) & 3;                                         \
                int slot = (half4 + (s4 ^ ((col >> 1) & 3))) ^ (col & 7);        \
                gl16((kss ? xpl1 : xpl0)                                         \
                         + ((size_t)(R0 + r) * 66 + col) * 128 + (slot << 4),    \
                     xs[kss][bf] + off);                                         \
            } else {                            /* A job */                      \
                int kss = (j >= 52);                                             \
                int jj = kss ? j - 52 : j - 34;                                  \
                gl16((kss ? apl1 : apl0) + jj * 1024 + (lane << 4),              \
                     as_[kss][bf] + jj * 1024);                                  \
            }                                                                    \
        }                                                                        \
    }

    f32x4 acc[2][2] = {};

    STAGE_CD(0, 0);

    #pragma unroll
    for (int ci = 0; ci < 8; ++ci) {
        int bf = ci & 1;
        if (ci < 7) {
            STAGE_CD(ci + 1, bf ^ 1);
            asm volatile("s_waitcnt vmcnt(9)" ::: "memory");
        } else {
            asm volatile("s_waitcnt vmcnt(0)" ::: "memory");
        }
        __builtin_amdgcn_sched_barrier(0);
        __builtin_amdgcn_s_barrier();
        __builtin_amdgcn_sched_barrier(0);

        const char* xb = xs[ks][bf];
        const char* ab = as_[ks][bf];
        #pragma unroll
        for (int kh = 0; kh < 3; ++kh) {
            #pragma unroll
            for (int kw = 0; kw < 3; ++kw) {
                const int kpos = kh * 3 + kw;
                short8 a0 = *(const short8*)(ab + (kpos * 2 + 0) * 1024 + (lane << 4));
                short8 a1 = *(const short8*)(ab + (kpos * 2 + 1) * 1024 + (lane << 4));
                int row = lr + kh;
                int g0 = colh * 32 + lo + kw;
                int g1 = g0 + 16;
                short8 b0 = *(const short8*)(xb + ((row * 66 + g0) << 6)
                                                + ((hi ^ ((g0 >> 1) & 3)) << 4));
                short8 b1 = *(const short8*)(xb + ((row * 66 + g1) << 6)
                                                + ((hi ^ ((g1 >> 1) & 3)) << 4));
                acc[0][0] = __builtin_amdgcn_mfma_f32_16x16x32_bf16(a0, b0, acc[0][0], 0, 0, 0);
                acc[0][1] = __builtin_amdgcn_mfma_f32_16x16x32_bf16(a0, b1, acc[0][1], 0, 0, 0);
                acc[1][0] = __builtin_amdgcn_mfma_f32_16x16x32_bf16(a1, b0, acc[1][0], 0, 0, 0);
                acc[1][1] = __builtin_amdgcn_mfma_f32_16x16x32_bf16(a1, b1, acc[1][1], 0, 0, 0);
            }
        }
        __builtin_amdgcn_sched_barrier(0);
        __builtin_amdgcn_s_barrier();
    }
#undef STAGE_CD

    // cross-wave K-reduce: ks=1 waves park acc in LDS scratch (buffer xs[1][0],
    // not read in last compute (bf=1), all gl16 drained by peeled vmcnt(0)).
    char* scr = &xs[1][0][0];
    if (ks == 1) {
        char* p = scr + (wv & 3) * 4096 + lane * 64;
        *(f32x4*)(p +  0) = acc[0][0];
        *(f32x4*)(p + 16) = acc[0][1];
        *(f32x4*)(p + 32) = acc[1][0];
        *(f32x4*)(p + 48) = acc[1][1];
    }
    __syncthreads();
    if (ks == 0) {
        const char* p = scr + (wv & 3) * 4096 + lane * 64;
        acc[0][0] += *(const f32x4*)(p +  0);
        acc[0][1] += *(const f32x4*)(p + 16);
        acc[1][0] += *(const f32x4*)(p + 32);
        acc[1][1] += *(const f32x4*)(p + 48);

        // epilogue: och = mt*16 + hi*4 + j, px col = colh*32 + nt*16 + lo
        int h = R0 + lr;
        #pragma unroll
        for (int nt = 0; nt < 2; ++nt) {
            int colp = colh * 32 + nt * 16 + lo + 1;
            short* ob = tp2 + ((size_t)(b * 66 + h + 1) * 80 + colp) * 32;
            #pragma unroll
            for (int mt = 0; mt < 2; ++mt) {
                f32x4 bd4 = *(const f32x4*)(bd_eff + b * 32 + mt * 16 + hi * 4);
                short4v sv;
                #pragma unroll
                for (int j = 0; j < 4; ++j) {
                    float f = acc[mt][nt][j] + bd4[j];
                    f = f > 0.f ? f : 0.2f * f;
                    sv[j] = f2bf(f);
                }
                int sl = mt * 2 + (hi >> 1);
                int slp = sl ^ (colp & 3);
                *(short4v*)(ob + slp * 8 + (hi & 1) * 4) = sv;
            }
        }
    }
}

// ---------------------------------------------------------------------------
// Kernel 6: conv_up + residual.  block = (b, 2 rows, 128 och). grid 1024.
// t-tile 4 rows x 80 x 32 = 20 KiB staged once (20 x gl16), 1 barrier,
// straight-line 9-kpos compute + 1-deep A prefetch. XCD swizzle: batch<->XCD.
// ---------------------------------------------------------------------------
__global__ __launch_bounds__(256, 3) void k_conv_up(const short* __restrict__ tp2,
                                                    const short* __restrict__ wu_frag,
                                                    const float* __restrict__ content,
                                                    const float* __restrict__ bu,
                                                    float* __restrict__ out) {
    __shared__ __align__(16) short tl[10240];   // 4 x 80 x 32
    int d = blockIdx.x;                 // 1024
    int nb = (d & 7) * 128 + (d >> 3);  // XCD x <-> batch x
    int ocq = nb & 3, hb = (nb >> 2) & 31, b = nb >> 7;
    int t = threadIdx.x, lane = t & 63, wv = t >> 6;
    int lr = wv >> 1, oh = wv & 1;
    int lo = lane & 15, hi = lane >> 4;
    int Ob = ocq * 128 + oh * 64;
    int R0 = 2 * hb;

    const char* sbase = (const char*)tp2 + ((size_t)(b * 66 + R0) * 80) * 64;
    for (int i = wv; i < 20; i += 4)
        gl16(sbase + i * 1024 + lane * 16, (char*)tl + i * 1024);

    const short* ab0 = wu_frag + ((size_t)(b * 9) * 32 + (Ob >> 4)) * 512
                     + lo * 32 + hi * 8;

    // preload kpos 0 A-frags while the gl16s are in flight
    short8 a_pre[4];
    #pragma unroll
    for (int mt = 0; mt < 4; ++mt)
        a_pre[mt] = *(const short8*)(ab0 + (size_t)mt * 512);

    __syncthreads();

    f32x4 acc[4][4] = {};

    #pragma unroll
    for (int kh = 0; kh < 3; ++kh) {
        #pragma unroll
        for (int kw = 0; kw < 3; ++kw) {
            const int kpos = kh * 3 + kw;
            short8 a_use[4];
            #pragma unroll
            for (int mt = 0; mt < 4; ++mt) a_use[mt] = a_pre[mt];
            if (kpos < 8) {
                #pragma unroll
                for (int mt = 0; mt < 4; ++mt)
                    a_pre[mt] = *(const short8*)(ab0 + ((size_t)(kpos + 1) * 32 + mt) * 512);
            }
            short8 bf0, bf1, bf2, bf3;
            #pragma unroll
            for (int nt = 0; nt < 4; ++nt) {
                int g = nt * 16 + lo + kw;                 // padded col 0..65
                short8 bf = *(const short8*)(tl + ((lr + kh) * 80 + g) * 32
                                                + ((hi ^ (g & 3)) << 3));
                if (nt == 0) bf0 = bf; else if (nt == 1) bf1 = bf;
                else if (nt == 2) bf2 = bf; else bf3 = bf;
            }
            #pragma unroll
            for (int mt = 0; mt < 4; ++mt) {
                acc[mt][0] = __builtin_amdgcn_mfma_f32_16x16x32_bf16(a_use[mt], bf0, acc[mt][0], 0, 0, 0);
                acc[mt][1] = __builtin_amdgcn_mfma_f32_16x16x32_bf16(a_use[mt], bf1, acc[mt][1], 0, 0, 0);
                acc[mt][2] = __builtin_amdgcn_mfma_f32_16x16x32_bf16(a_use[mt], bf2, acc[mt][2], 0, 0, 0);
                acc[mt][3] = __builtin_amdgcn_mfma_f32_16x16x32_bf16(a_use[mt], bf3, acc[mt][3], 0, 0, 0);
            }
        }
    }

    int h = R0 + lr;
    #pragma unroll
    for (int mt = 0; mt < 4; ++mt) {
        f32x4 bu4 = *(const f32x4*)(bu + Ob + mt * 16 + hi * 4);
        #pragma unroll
        for (int nt = 0; nt < 4; ++nt) {
            int px = nt * 16 + lo;
            #pragma unroll
            for (int j = 0; j < 4; ++j) {
                int O = Ob + mt * 16 + hi * 4 + j;
                size_t gidx = (((size_t)(b * 512 + O) * 64) + h) * 64 + px;
                out[gidx] = acc[mt][nt][j] + content[gidx] + bu4[j];
            }
        }
    }
}

// ---------------------------------------------------------------------------
extern "C" void kernel_launch(void* const* d_in, const int* in_sizes, int n_in,
                              void* d_out, int out_size, void* d_ws, size_t ws_size,
                              hipStream_t stream) {
    const float* content = (const float*)d_in[0];
    const float* f1      = (const float*)d_in[1];
    const float* f2      = (const float*)d_in[2];
    const float* wd      = (const float*)d_in[3];
    const float* bd      = (const float*)d_in[4];
    const float* wu      = (const float*)d_in[5];
    const float* bu      = (const float*)d_in[6];
    float* out = (float*)d_out;

    char* ws = (char*)d_ws;
    // layout (bytes):
    //   xTc    [8][8][66][66][64] bf16 : 35,684,352
    //   wd_frag                        :  2,359,296
    //   wu_frag                        :  2,359,296
    //   bd_eff                         :      1,024
    //   tp2    [8][66][80][32] bf16    :  2,703,360   (total ~43.1 MiB)
    short* xTc     = (short*)(ws);
    short* wd_frag = (short*)(ws + 35684352);
    short* wu_frag = (short*)(ws + 38043648);
    float* bd_eff  = (float*)(ws + 40402944);
    short* tp2     = (short*)(ws + 40403968);

    k_zero_halo<<<dim3(520),  dim3(256), 0, stream>>>(xTc, 64, 66, 8);
    k_zero_halo<<<dim3(33),   dim3(256), 0, stream>>>(tp2, 8, 80, 4);
    k_transpose<<<dim3(1024), dim3(256), 0, stream>>>(content, xTc);
    k_fold1    <<<dim3(512),  dim3(256), 0, stream>>>(f1, wd, wd_frag);
    k_fold2    <<<dim3(512),  dim3(256), 0, stream>>>(f2, wu, wu_frag);
    k_bd       <<<dim3(1),    dim3(256), 0, stream>>>(f1, bd, bd_eff);
    k_conv_down<<<dim3(256),  dim3(512), 0, stream>>>((const char*)xTc,
                                                      (const char*)wd_frag,
                                                      bd_eff, tp2);
    k_conv_up  <<<dim3(1024), dim3(256), 0, stream>>>(tp2, wu_frag, content, bu, out);
}

// Round 11
// 93.402 us; speedup vs baseline: 1.2458x; 1.0091x over previous
//
#include <hip/hip_runtime.h>
#include <hip/hip_bf16.h>

typedef __attribute__((ext_vector_type(8)))  short short8;
typedef __attribute__((ext_vector_type(4)))  short short4v;
typedef __attribute__((ext_vector_type(4)))  float f32x4;

static __device__ inline short f2bf(float f) {
    union { __hip_bfloat16 h; unsigned short u; } cv;
    cv.h = __float2bfloat16(f);
    return (short)cv.u;
}

typedef __attribute__((address_space(3))) void lds_void;
typedef const __attribute__((address_space(1))) void glob_void;
static __device__ inline void gl16(const void* g, void* l) {
    // global -> LDS direct copy, 16 B/lane (1 KiB/wave). LDS dest must be
    // wave-uniform base (+ lane*16 HW-added); global src is per-lane.
    __builtin_amdgcn_global_load_lds((glob_void*)g, (lds_void*)l, 16, 0, 0);
}

// ---------------------------------------------------------------------------
// Kernel 0: zero halo of padded [nimg][66][rs][ch8*8] bf16 buffer (cols 0..65).
// ---------------------------------------------------------------------------
__global__ __launch_bounds__(256) void k_zero_halo(short* __restrict__ p, int nimg,
                                                   int rs, int ch8) {
    int id = blockIdx.x * 256 + threadIdx.x;
    int njobs = nimg * 260 * ch8;
    if (id >= njobs) return;
    int c8 = id % ch8;
    int rest = id / ch8;
    int px = rest % 260;
    int img = rest / 260;
    int row, col;
    if (px < 66)       { row = 0;  col = px; }
    else if (px < 132) { row = 65; col = px - 66; }
    else { int q = px - 132; row = 1 + (q >> 1); col = (q & 1) ? 65 : 0; }
    short8 z = {0, 0, 0, 0, 0, 0, 0, 0};
    *(short8*)(p + ((size_t)(img * 66 + row) * rs + col) * (ch8 * 8) + c8 * 8) = z;
}

// ---------------------------------------------------------------------------
// Kernel 1: content [B,512,64,64] f32 -> xTc [b][cs8][66][66][64] bf16,
// interior only, pre-swizzled within each 128B pixel-block: slot ^= (colp&7).
// ---------------------------------------------------------------------------
__global__ __launch_bounds__(256) void k_transpose(const float* __restrict__ x,
                                                   short* __restrict__ xTc) {
    __shared__ float lds[128][65];
    int blk = blockIdx.x;
    int half = blk & 1;
    int h = (blk >> 1) & 63;
    int b = blk >> 7;
    int t = threadIdx.x;
    for (int q = 0; q < 2; ++q) {
        int cb = half * 2 + q;
        #pragma unroll
        for (int k = 0; k < 8; ++k) {
            int idx = k * 256 + t;          // 2048 jobs: (c, 4-float group)
            int c = idx >> 4, wq = idx & 15;
            f32x4 v = *(const f32x4*)(x + (((size_t)b * 512 + cb * 128 + c) * 64 + h) * 64
                                        + wq * 4);
            lds[c][wq * 4 + 0] = v.x;
            lds[c][wq * 4 + 1] = v.y;
            lds[c][wq * 4 + 2] = v.z;
            lds[c][wq * 4 + 3] = v.w;
        }
        __syncthreads();
        #pragma unroll
        for (int k = 0; k < 4; ++k) {
            int j = k * 256 + t;       // 1024 jobs: (w, 16B-slot of 128 ch)
            int w = j >> 4, sl = j & 15;
            int cs = cb * 2 + (sl >> 3);
            int slotp = (sl & 7) ^ ((w + 1) & 7);
            short8 v;
            #pragma unroll
            for (int e = 0; e < 8; ++e) v[e] = f2bf(lds[sl * 8 + e][w]);
            *(short8*)(xTc + (((size_t)(b * 8 + cs) * 66 + (h + 1)) * 66 + (w + 1)) * 64
                           + slotp * 8) = v;
        }
        __syncthreads();
    }
}

// ---------------------------------------------------------------------------
// Kernel 2: Wd_eff fragment-major, chunk=32ch, LANE-LINEAR frags:
// wd_frag[b][ci16][kpos9][mt2][512]; elem (hi*16+lo)*8+e holds
// Wd_eff[och=mt*16+lo][ch=ci*32+hi*8+e]  -> gl16-stageable + conflict-free.
// ---------------------------------------------------------------------------
__global__ __launch_bounds__(256) void k_fold1(const float* __restrict__ f1,
                                               const float* __restrict__ wd,
                                               short* __restrict__ wd_frag) {
    int id = blockIdx.x * 256 + threadIdx.x;
    int i = id & 511;
    int o = (id >> 9) & 31;
    int b = id >> 14;
    float acc[9];
    #pragma unroll
    for (int k = 0; k < 9; ++k) acc[k] = 0.f;
    for (int m = 0; m < 32; ++m) {
        float f = f1[(b * 32 + o) * 32 + m];
        const float* wrow = wd + ((size_t)m * 512 + i) * 9;
        #pragma unroll
        for (int k = 0; k < 9; ++k) acc[k] += f * wrow[k];
    }
    int ci = i >> 5, hi = (i >> 3) & 3, e = i & 7;
    int mt = o >> 4, lo = o & 15;
    #pragma unroll
    for (int k = 0; k < 9; ++k)
        wd_frag[(((size_t)(b * 16 + ci) * 9 + k) * 2 + mt) * 512
                + hi * 128 + lo * 8 + e] = f2bf(acc[k]);
}

// ---------------------------------------------------------------------------
// Kernel 3: Wu_eff fragment-major: wu_frag[b][kpos9][g32][512]
// thread = (b, O, c); wu row (288B) dense + wave-uniform; acc over all kpos.
// ---------------------------------------------------------------------------
__global__ __launch_bounds__(256) void k_fold2(const float* __restrict__ f2,
                                               const float* __restrict__ wu,
                                               short* __restrict__ wu_frag) {
    int id = blockIdx.x * 256 + threadIdx.x;   // (b*512+O)*32 + c
    int c = id & 31;
    int O = (id >> 5) & 511;
    int b = id >> 14;
    float acc[9];
    #pragma unroll
    for (int k = 0; k < 9; ++k) acc[k] = 0.f;
    for (int m = 0; m < 32; ++m) {
        float f = f2[(b * 32 + m) * 32 + c];
        const float* wr = wu + ((size_t)O * 32 + m) * 9;
        #pragma unroll
        for (int k = 0; k < 9; ++k) acc[k] += wr[k] * f;
    }
    int g = O >> 4, lo = O & 15, hi = c >> 3, e = c & 7;
    #pragma unroll
    for (int k = 0; k < 9; ++k)
        wu_frag[((size_t)(b * 9 + k) * 32 + g) * 512 + lo * 32 + hi * 8 + e]
            = f2bf(acc[k]);
}

// ---------------------------------------------------------------------------
// Kernel 4: bd_eff[b][o] = sum_m F1[b,o,m] * bd[m]
// ---------------------------------------------------------------------------
__global__ void k_bd(const float* __restrict__ f1, const float* __restrict__ bd,
                     float* __restrict__ bd_eff) {
    int t = threadIdx.x;
    int b = t >> 5, o = t & 31;
    float acc = 0.f;
    #pragma unroll
    for (int m = 0; m < 32; ++m) acc += f1[(b * 32 + o) * 32 + m] * bd[m];
    bd_eff[t] = acc;
}

// ---------------------------------------------------------------------------
// Kernel 5: conv_down, K-split pipelined (unchanged from R10).
// ---------------------------------------------------------------------------
__global__ __launch_bounds__(512) void k_conv_down(const char* __restrict__ xTc,
                                                   const char* __restrict__ wd_frag,
                                                   const float* __restrict__ bd_eff,
                                                   short* __restrict__ tp2) {
    __shared__ __align__(16) char xs[2][2][16896];   // [ks][buf][4r x 66c x 64B]
    __shared__ __align__(16) char as_[2][2][18432];  // [ks][buf][9 kpos][2 mt][1KB]
    int d = blockIdx.x;                // 256
    int nb = (d & 7) * 32 + (d >> 3);  // XCD <-> batch swizzle
    int b = nb >> 5, rp = nb & 31;
    int R0 = rp * 2;
    int t = threadIdx.x, lane = t & 63, wv = t >> 6;   // wv 0..7
    int ks = wv >> 2, lr = (wv >> 1) & 1, colh = wv & 1;
    int lo = lane & 15, hi = lane >> 4;

    const char* wdb = wd_frag + (size_t)(b * 16) * 18432;
    const char* xbb = xTc + (size_t)(b * 8) * 557568;

#define STAGE_CD(ci, bf)                                                         \
    {                                                                            \
        const int cc0 = (ci);                                                    \
        const int half4 = (cc0 & 1) * 4;                                         \
        const char* xpl0 = xbb + (size_t)(cc0 >> 1) * 557568;                    \
        const char* xpl1 = xpl0 + (size_t)4 * 557568;                            \
        const char* apl0 = wdb + (size_t)cc0 * 18432;                            \
        const char* apl1 = apl0 + (size_t)8 * 18432;                             \
        _Pragma("unroll")                                                        \
        for (int i2 = 0; i2 < 9; ++i2) {                                         \
            int j = wv * 9 + i2;                                                 \
            if (j >= 70) j -= 70;                                                \
            if (j < 34) {                       /* x job */                      \
                int kss = (j >= 17);                                             \
                int jj = kss ? j - 17 : j;                                       \
                int off = (jj < 16) ? jj * 1024 : 15872;                         \
                int dd = off + (lane << 4);                                      \
                int r = dd / 4224;                                               \
                int rem = dd - r * 4224;                                         \
                int col = rem >> 6;                                              \
                int s4 = (rem >> 4) & 3;                                         \
                int slot = (half4 + (s4 ^ ((col >> 1) & 3))) ^ (col & 7);        \
                gl16((kss ? xpl1 : xpl0)                                         \
                         + ((size_t)(R0 + r) * 66 + col) * 128 + (slot << 4),    \
                     xs[kss][bf] + off);                                         \
            } else {                            /* A job */                      \
                int kss = (j >= 52);                                             \
                int jj = kss ? j - 52 : j - 34;                                  \
                gl16((kss ? apl1 : apl0) + jj * 1024 + (lane << 4),              \
                     as_[kss][bf] + jj * 1024);                                  \
            }                                                                    \
        }                                                                        \
    }

    f32x4 acc[2][2] = {};

    STAGE_CD(0, 0);

    #pragma unroll
    for (int ci = 0; ci < 8; ++ci) {
        int bf = ci & 1;
        if (ci < 7) {
            STAGE_CD(ci + 1, bf ^ 1);
            asm volatile("s_waitcnt vmcnt(9)" ::: "memory");
        } else {
            asm volatile("s_waitcnt vmcnt(0)" ::: "memory");
        }
        __builtin_amdgcn_sched_barrier(0);
        __builtin_amdgcn_s_barrier();
        __builtin_amdgcn_sched_barrier(0);

        const char* xb = xs[ks][bf];
        const char* ab = as_[ks][bf];
        #pragma unroll
        for (int kh = 0; kh < 3; ++kh) {
            #pragma unroll
            for (int kw = 0; kw < 3; ++kw) {
                const int kpos = kh * 3 + kw;
                short8 a0 = *(const short8*)(ab + (kpos * 2 + 0) * 1024 + (lane << 4));
                short8 a1 = *(const short8*)(ab + (kpos * 2 + 1) * 1024 + (lane << 4));
                int row = lr + kh;
                int g0 = colh * 32 + lo + kw;
                int g1 = g0 + 16;
                short8 b0 = *(const short8*)(xb + ((row * 66 + g0) << 6)
                                                + ((hi ^ ((g0 >> 1) & 3)) << 4));
                short8 b1 = *(const short8*)(xb + ((row * 66 + g1) << 6)
                                                + ((hi ^ ((g1 >> 1) & 3)) << 4));
                acc[0][0] = __builtin_amdgcn_mfma_f32_16x16x32_bf16(a0, b0, acc[0][0], 0, 0, 0);
                acc[0][1] = __builtin_amdgcn_mfma_f32_16x16x32_bf16(a0, b1, acc[0][1], 0, 0, 0);
                acc[1][0] = __builtin_amdgcn_mfma_f32_16x16x32_bf16(a1, b0, acc[1][0], 0, 0, 0);
                acc[1][1] = __builtin_amdgcn_mfma_f32_16x16x32_bf16(a1, b1, acc[1][1], 0, 0, 0);
            }
        }
        __builtin_amdgcn_sched_barrier(0);
        __builtin_amdgcn_s_barrier();
    }
#undef STAGE_CD

    // cross-wave K-reduce via LDS scratch (all gl16 drained by peeled vmcnt(0)).
    char* scr = &xs[1][0][0];
    if (ks == 1) {
        char* p = scr + (wv & 3) * 4096 + lane * 64;
        *(f32x4*)(p +  0) = acc[0][0];
        *(f32x4*)(p + 16) = acc[0][1];
        *(f32x4*)(p + 32) = acc[1][0];
        *(f32x4*)(p + 48) = acc[1][1];
    }
    __syncthreads();
    if (ks == 0) {
        const char* p = scr + (wv & 3) * 4096 + lane * 64;
        acc[0][0] += *(const f32x4*)(p +  0);
        acc[0][1] += *(const f32x4*)(p + 16);
        acc[1][0] += *(const f32x4*)(p + 32);
        acc[1][1] += *(const f32x4*)(p + 48);

        int h = R0 + lr;
        #pragma unroll
        for (int nt = 0; nt < 2; ++nt) {
            int colp = colh * 32 + nt * 16 + lo + 1;
            short* ob = tp2 + ((size_t)(b * 66 + h + 1) * 80 + colp) * 32;
            #pragma unroll
            for (int mt = 0; mt < 2; ++mt) {
                f32x4 bd4 = *(const f32x4*)(bd_eff + b * 32 + mt * 16 + hi * 4);
                short4v sv;
                #pragma unroll
                for (int j = 0; j < 4; ++j) {
                    float f = acc[mt][nt][j] + bd4[j];
                    f = f > 0.f ? f : 0.2f * f;
                    sv[j] = f2bf(f);
                }
                int sl = mt * 2 + (hi >> 1);
                int slp = sl ^ (colp & 3);
                *(short4v*)(ob + slp * 8 + (hi & 1) * 4) = sv;
            }
        }
    }
}

// ---------------------------------------------------------------------------
// Kernel 6: conv_up + residual, A-staged pipeline.
// block = (b, 2 rows, 128 och). grid 1024, 4 waves; wave = 64 och x 64 px.
// t-tile 20KB staged once; A (wu_frag) staged per-kpos via gl16: 8KB/kpos,
// TRIPLE-buffered depth-2 prefetch, counted vmcnt(4/2/0) + raw s_barrier
// (R10's 1-deep register prefetch left a CU-serial ~300cyc L2 chain per
// kpos: same-CU blocks shared ocq = same A addresses). nb redecode puts
// ocq in slow bits: co-resident blocks share the t-tile but read DIFFERENT
// wu_frag regions. LDS 44KB -> 3 blocks/CU.
// ---------------------------------------------------------------------------
__global__ __launch_bounds__(256, 3) void k_conv_up(const short* __restrict__ tp2,
                                                    const short* __restrict__ wu_frag,
                                                    const float* __restrict__ content,
                                                    const float* __restrict__ bu,
                                                    float* __restrict__ out) {
    __shared__ __align__(16) short tl[10240];     // 4 x 80 x 32
    __shared__ __align__(16) char au[3][8192];    // [buf][8 g][1KB frag]
    int d = blockIdx.x;                 // 1024
    int nb = (d & 7) * 128 + (d >> 3);  // XCD x <-> batch x
    int b = nb >> 7, ocq = (nb >> 5) & 3, hb = nb & 31;
    int t = threadIdx.x, lane = t & 63, wv = t >> 6;
    int lr = wv >> 1, oh = wv & 1;
    int lo = lane & 15, hi = lane >> 4;
    int Ob = ocq * 128 + oh * 64;
    int R0 = 2 * hb;

    const char* sbase = (const char*)tp2 + ((size_t)(b * 66 + R0) * 80) * 64;
    #pragma unroll
    for (int i = 0; i < 5; ++i)
        gl16(sbase + (wv * 5 + i) * 1024 + lane * 16, (char*)tl + (wv * 5 + i) * 1024);

    // A source: g-frags [ocq*8 .. ocq*8+8) per kpos; kpos stride = 32 KB.
    const char* abase = (const char*)wu_frag + ((size_t)(b * 9) * 32 + ocq * 8) * 1024;
    #pragma unroll
    for (int k0 = 0; k0 < 2; ++k0)        // prologue: stage A[0], A[1]
        #pragma unroll
        for (int i = 0; i < 2; ++i)
            gl16(abase + (size_t)k0 * 32768 + (wv * 2 + i) * 1024 + lane * 16,
                 au[k0] + (wv * 2 + i) * 1024);

    asm volatile("s_waitcnt vmcnt(0)" ::: "memory");
    __builtin_amdgcn_sched_barrier(0);
    __builtin_amdgcn_s_barrier();
    __builtin_amdgcn_sched_barrier(0);

    f32x4 acc[4][4] = {};
    const int aoff = oh * 4096 + lo * 64 + hi * 16;   // wave's byte base in au[]

    #pragma unroll
    for (int kh = 0; kh < 3; ++kh) {
        #pragma unroll
        for (int kw = 0; kw < 3; ++kw) {
            const int kpos = kh * 3 + kw;
            if (kpos < 7) {
                #pragma unroll
                for (int i = 0; i < 2; ++i)
                    gl16(abase + (size_t)(kpos + 2) * 32768 + (wv * 2 + i) * 1024
                             + lane * 16,
                         au[(kpos + 2) % 3] + (wv * 2 + i) * 1024);
                asm volatile("s_waitcnt vmcnt(4)" ::: "memory");
            } else if (kpos == 7) {
                asm volatile("s_waitcnt vmcnt(2)" ::: "memory");
            } else {
                asm volatile("s_waitcnt vmcnt(0)" ::: "memory");
            }
            __builtin_amdgcn_sched_barrier(0);
            __builtin_amdgcn_s_barrier();
            __builtin_amdgcn_sched_barrier(0);

            const char* ab = au[kpos % 3];
            short8 bf0, bf1, bf2, bf3;
            #pragma unroll
            for (int nt = 0; nt < 4; ++nt) {
                int g = nt * 16 + lo + kw;                 // padded col 0..65
                short8 bf = *(const short8*)(tl + ((lr + kh) * 80 + g) * 32
                                                + ((hi ^ (g & 3)) << 3));
                if (nt == 0) bf0 = bf; else if (nt == 1) bf1 = bf;
                else if (nt == 2) bf2 = bf; else bf3 = bf;
            }
            #pragma unroll
            for (int mt = 0; mt < 4; ++mt) {
                short8 af = *(const short8*)(ab + mt * 1024 + aoff);
                acc[mt][0] = __builtin_amdgcn_mfma_f32_16x16x32_bf16(af, bf0, acc[mt][0], 0, 0, 0);
                acc[mt][1] = __builtin_amdgcn_mfma_f32_16x16x32_bf16(af, bf1, acc[mt][1], 0, 0, 0);
                acc[mt][2] = __builtin_amdgcn_mfma_f32_16x16x32_bf16(af, bf2, acc[mt][2], 0, 0, 0);
                acc[mt][3] = __builtin_amdgcn_mfma_f32_16x16x32_bf16(af, bf3, acc[mt][3], 0, 0, 0);
            }
            __builtin_amdgcn_sched_barrier(0);
            __builtin_amdgcn_s_barrier();
        }
    }

    int h = R0 + lr;
    #pragma unroll
    for (int mt = 0; mt < 4; ++mt) {
        f32x4 bu4 = *(const f32x4*)(bu + Ob + mt * 16 + hi * 4);
        #pragma unroll
        for (int nt = 0; nt < 4; ++nt) {
            int px = nt * 16 + lo;
            #pragma unroll
            for (int j = 0; j < 4; ++j) {
                int O = Ob + mt * 16 + hi * 4 + j;
                size_t gidx = (((size_t)(b * 512 + O) * 64) + h) * 64 + px;
                out[gidx] = acc[mt][nt][j] + content[gidx] + bu4[j];
            }
        }
    }
}

// ---------------------------------------------------------------------------
extern "C" void kernel_launch(void* const* d_in, const int* in_sizes, int n_in,
                              void* d_out, int out_size, void* d_ws, size_t ws_size,
                              hipStream_t stream) {
    const float* content = (const float*)d_in[0];
    const float* f1      = (const float*)d_in[1];
    const float* f2      = (const float*)d_in[2];
    const float* wd      = (const float*)d_in[3];
    const float* bd      = (const float*)d_in[4];
    const float* wu      = (const float*)d_in[5];
    const float* bu      = (const float*)d_in[6];
    float* out = (float*)d_out;

    char* ws = (char*)d_ws;
    // layout (bytes):
    //   xTc    [8][8][66][66][64] bf16 : 35,684,352
    //   wd_frag                        :  2,359,296
    //   wu_frag                        :  2,359,296
    //   bd_eff                         :      1,024
    //   tp2    [8][66][80][32] bf16    :  2,703,360   (total ~43.1 MiB)
    short* xTc     = (short*)(ws);
    short* wd_frag = (short*)(ws + 35684352);
    short* wu_frag = (short*)(ws + 38043648);
    float* bd_eff  = (float*)(ws + 40402944);
    short* tp2     = (short*)(ws + 40403968);

    k_zero_halo<<<dim3(520),  dim3(256), 0, stream>>>(xTc, 64, 66, 8);
    k_zero_halo<<<dim3(33),   dim3(256), 0, stream>>>(tp2, 8, 80, 4);
    k_transpose<<<dim3(1024), dim3(256), 0, stream>>>(content, xTc);
    k_fold1    <<<dim3(512),  dim3(256), 0, stream>>>(f1, wd, wd_frag);
    k_fold2    <<<dim3(512),  dim3(256), 0, stream>>>(f2, wu, wu_frag);
    k_bd       <<<dim3(1),    dim3(256), 0, stream>>>(f1, bd, bd_eff);
    k_conv_down<<<dim3(256),  dim3(512), 0, stream>>>((const char*)xTc,
                                                      (const char*)wd_frag,
                                                      bd_eff, tp2);
    k_conv_up  <<<dim3(1024), dim3(256), 0, stream>>>(tp2, wu_frag, content, bu, out);
}

// Round 12
// 78.528 us; speedup vs baseline: 1.4818x; 1.1894x over previous
//
#include <hip/hip_runtime.h>
#include <hip/hip_bf16.h>

typedef __attribute__((ext_vector_type(8)))  short short8;
typedef __attribute__((ext_vector_type(4)))  short short4v;
typedef __attribute__((ext_vector_type(4)))  float f32x4;

static __device__ inline short f2bf(float f) {
    union { __hip_bfloat16 h; unsigned short u; } cv;
    cv.h = __float2bfloat16(f);
    return (short)cv.u;
}

typedef __attribute__((address_space(3))) void lds_void;
typedef const __attribute__((address_space(1))) void glob_void;
static __device__ inline void gl16(const void* g, void* l) {
    // global -> LDS direct copy, 16 B/lane (1 KiB/wave). LDS dest must be
    // wave-uniform base (+ lane*16 HW-added); global src is per-lane.
    __builtin_amdgcn_global_load_lds((glob_void*)g, (lds_void*)l, 16, 0, 0);
}

// ---------------------------------------------------------------------------
// Kernel 1: k_prep — ALL prep work in ONE dispatch (kills 5 launch gaps):
//   blocks [0,1024)    : content f32 NCHW -> xTc bf16 channel-last (swizzled)
//   blocks [1024,1536) : fold1 -> wd_frag (lane-linear frags)
//   blocks [1536,2048) : fold2 -> wu_frag
//   blocks [2048,2568) : zero halo of xTc
//   blocks [2568,2601) : zero halo of tp2
//   block  2601        : bd_eff
// All roles independent, read only inputs; xTc interior/halo are disjoint.
// ---------------------------------------------------------------------------
__global__ __launch_bounds__(256) void k_prep(const float* __restrict__ x,
                                              const float* __restrict__ f1,
                                              const float* __restrict__ f2,
                                              const float* __restrict__ wd,
                                              const float* __restrict__ bd,
                                              const float* __restrict__ wu,
                                              short* __restrict__ xTc,
                                              short* __restrict__ wd_frag,
                                              short* __restrict__ wu_frag,
                                              float* __restrict__ bd_eff,
                                              short* __restrict__ tp2) {
    __shared__ float lds[128][65];
    int blk = blockIdx.x;
    int t = threadIdx.x;

    if (blk < 1024) {
        // ---- transpose role ----
        int half = blk & 1;
        int h = (blk >> 1) & 63;
        int b = blk >> 7;
        for (int q = 0; q < 2; ++q) {
            int cb = half * 2 + q;
            #pragma unroll
            for (int k = 0; k < 8; ++k) {
                int idx = k * 256 + t;          // 2048 jobs: (c, 4-float group)
                int c = idx >> 4, wq = idx & 15;
                f32x4 v = *(const f32x4*)(x + (((size_t)b * 512 + cb * 128 + c) * 64 + h) * 64
                                            + wq * 4);
                lds[c][wq * 4 + 0] = v.x;
                lds[c][wq * 4 + 1] = v.y;
                lds[c][wq * 4 + 2] = v.z;
                lds[c][wq * 4 + 3] = v.w;
            }
            __syncthreads();
            #pragma unroll
            for (int k = 0; k < 4; ++k) {
                int j = k * 256 + t;       // 1024 jobs: (w, 16B-slot of 128 ch)
                int w = j >> 4, sl = j & 15;
                int cs = cb * 2 + (sl >> 3);
                int slotp = (sl & 7) ^ ((w + 1) & 7);
                short8 v;
                #pragma unroll
                for (int e = 0; e < 8; ++e) v[e] = f2bf(lds[sl * 8 + e][w]);
                *(short8*)(xTc + (((size_t)(b * 8 + cs) * 66 + (h + 1)) * 66 + (w + 1)) * 64
                               + slotp * 8) = v;
            }
            __syncthreads();
        }
    } else if (blk < 1536) {
        // ---- fold1 role: wd_frag[b][ci16][kpos9][mt2][512], lane-linear ----
        int id = (blk - 1024) * 256 + t;
        int i = id & 511;
        int o = (id >> 9) & 31;
        int b = id >> 14;
        float acc[9];
        #pragma unroll
        for (int k = 0; k < 9; ++k) acc[k] = 0.f;
        for (int m = 0; m < 32; ++m) {
            float f = f1[(b * 32 + o) * 32 + m];
            const float* wrow = wd + ((size_t)m * 512 + i) * 9;
            #pragma unroll
            for (int k = 0; k < 9; ++k) acc[k] += f * wrow[k];
        }
        int ci = i >> 5, hi = (i >> 3) & 3, e = i & 7;
        int mt = o >> 4, lo = o & 15;
        #pragma unroll
        for (int k = 0; k < 9; ++k)
            wd_frag[(((size_t)(b * 16 + ci) * 9 + k) * 2 + mt) * 512
                    + hi * 128 + lo * 8 + e] = f2bf(acc[k]);
    } else if (blk < 2048) {
        // ---- fold2 role: wu_frag[b][kpos9][g32][512] ----
        int id = (blk - 1536) * 256 + t;
        int c = id & 31;
        int O = (id >> 5) & 511;
        int b = id >> 14;
        float acc[9];
        #pragma unroll
        for (int k = 0; k < 9; ++k) acc[k] = 0.f;
        for (int m = 0; m < 32; ++m) {
            float f = f2[(b * 32 + m) * 32 + c];
            const float* wr = wu + ((size_t)O * 32 + m) * 9;
            #pragma unroll
            for (int k = 0; k < 9; ++k) acc[k] += wr[k] * f;
        }
        int g = O >> 4, lo = O & 15, hi = c >> 3, e = c & 7;
        #pragma unroll
        for (int k = 0; k < 9; ++k)
            wu_frag[((size_t)(b * 9 + k) * 32 + g) * 512 + lo * 32 + hi * 8 + e]
                = f2bf(acc[k]);
    } else if (blk < 2568) {
        // ---- zero halo of xTc: [64 img][66][66][64] ----
        int id = (blk - 2048) * 256 + t;
        if (id < 64 * 260 * 8) {
            int c8 = id % 8;
            int rest = id / 8;
            int px = rest % 260;
            int img = rest / 260;
            int row, col;
            if (px < 66)       { row = 0;  col = px; }
            else if (px < 132) { row = 65; col = px - 66; }
            else { int q = px - 132; row = 1 + (q >> 1); col = (q & 1) ? 65 : 0; }
            short8 z = {0, 0, 0, 0, 0, 0, 0, 0};
            *(short8*)(xTc + ((size_t)(img * 66 + row) * 66 + col) * 64 + c8 * 8) = z;
        }
    } else if (blk < 2601) {
        // ---- zero halo of tp2: [8 img][66][80][32] ----
        int id = (blk - 2568) * 256 + t;
        if (id < 8 * 260 * 4) {
            int c8 = id % 4;
            int rest = id / 4;
            int px = rest % 260;
            int img = rest / 260;
            int row, col;
            if (px < 66)       { row = 0;  col = px; }
            else if (px < 132) { row = 65; col = px - 66; }
            else { int q = px - 132; row = 1 + (q >> 1); col = (q & 1) ? 65 : 0; }
            short8 z = {0, 0, 0, 0, 0, 0, 0, 0};
            *(short8*)(tp2 + ((size_t)(img * 66 + row) * 80 + col) * 32 + c8 * 8) = z;
        }
    } else {
        // ---- bd role ----
        int b = t >> 5, o = t & 31;
        float acc = 0.f;
        #pragma unroll
        for (int m = 0; m < 32; ++m) acc += f1[(b * 32 + o) * 32 + m] * bd[m];
        bd_eff[t] = acc;
    }
}

// ---------------------------------------------------------------------------
// Kernel 2: conv_down, K-split pipelined (unchanged from R10/R11).
// ---------------------------------------------------------------------------
__global__ __launch_bounds__(512) void k_conv_down(const char* __restrict__ xTc,
                                                   const char* __restrict__ wd_frag,
                                                   const float* __restrict__ bd_eff,
                                                   short* __restrict__ tp2) {
    __shared__ __align__(16) char xs[2][2][16896];   // [ks][buf][4r x 66c x 64B]
    __shared__ __align__(16) char as_[2][2][18432];  // [ks][buf][9 kpos][2 mt][1KB]
    int d = blockIdx.x;                // 256
    int nb = (d & 7) * 32 + (d >> 3);  // XCD <-> batch swizzle
    int b = nb >> 5, rp = nb & 31;
    int R0 = rp * 2;
    int t = threadIdx.x, lane = t & 63, wv = t >> 6;   // wv 0..7
    int ks = wv >> 2, lr = (wv >> 1) & 1, colh = wv & 1;
    int lo = lane & 15, hi = lane >> 4;

    const char* wdb = wd_frag + (size_t)(b * 16) * 18432;
    const char* xbb = xTc + (size_t)(b * 8) * 557568;

#define STAGE_CD(ci, bf)                                                         \
    {                                                                            \
        const int cc0 = (ci);                                                    \
        const int half4 = (cc0 & 1) * 4;                                         \
        const char* xpl0 = xbb + (size_t)(cc0 >> 1) * 557568;                    \
        const char* xpl1 = xpl0 + (size_t)4 * 557568;                            \
        const char* apl0 = wdb + (size_t)cc0 * 18432;                            \
        const char* apl1 = apl0 + (size_t)8 * 18432;                             \
        _Pragma("unroll")                                                        \
        for (int i2 = 0; i2 < 9; ++i2) {                                         \
            int j = wv * 9 + i2;                                                 \
            if (j >= 70) j -= 70;                                                \
            if (j < 34) {                       /* x job */                      \
                int kss = (j >= 17);                                             \
                int jj = kss ? j - 17 : j;                                       \
                int off = (jj < 16) ? jj * 1024 : 15872;                         \
                int dd = off + (lane << 4);                                      \
                int r = dd / 4224;                                               \
                int rem = dd - r * 4224;                                         \
                int col = rem >> 6;                                              \
                int s4 = (rem >> 4) & 3;                                         \
                int slot = (half4 + (s4 ^ ((col >> 1) & 3))) ^ (col & 7);        \
                gl16((kss ? xpl1 : xpl0)                                         \
                         + ((size_t)(R0 + r) * 66 + col) * 128 + (slot << 4),    \
                     xs[kss][bf] + off);                                         \
            } else {                            /* A job */                      \
                int kss = (j >= 52);                                             \
                int jj = kss ? j - 52 : j - 34;                                  \
                gl16((kss ? apl1 : apl0) + jj * 1024 + (lane << 4),              \
                     as_[kss][bf] + jj * 1024);                                  \
            }                                                                    \
        }                                                                        \
    }

    f32x4 acc[2][2] = {};

    STAGE_CD(0, 0);

    #pragma unroll
    for (int ci = 0; ci < 8; ++ci) {
        int bf = ci & 1;
        if (ci < 7) {
            STAGE_CD(ci + 1, bf ^ 1);
            asm volatile("s_waitcnt vmcnt(9)" ::: "memory");
        } else {
            asm volatile("s_waitcnt vmcnt(0)" ::: "memory");
        }
        __builtin_amdgcn_sched_barrier(0);
        __builtin_amdgcn_s_barrier();
        __builtin_amdgcn_sched_barrier(0);

        const char* xb = xs[ks][bf];
        const char* ab = as_[ks][bf];
        #pragma unroll
        for (int kh = 0; kh < 3; ++kh) {
            #pragma unroll
            for (int kw = 0; kw < 3; ++kw) {
                const int kpos = kh * 3 + kw;
                short8 a0 = *(const short8*)(ab + (kpos * 2 + 0) * 1024 + (lane << 4));
                short8 a1 = *(const short8*)(ab + (kpos * 2 + 1) * 1024 + (lane << 4));
                int row = lr + kh;
                int g0 = colh * 32 + lo + kw;
                int g1 = g0 + 16;
                short8 b0 = *(const short8*)(xb + ((row * 66 + g0) << 6)
                                                + ((hi ^ ((g0 >> 1) & 3)) << 4));
                short8 b1 = *(const short8*)(xb + ((row * 66 + g1) << 6)
                                                + ((hi ^ ((g1 >> 1) & 3)) << 4));
                acc[0][0] = __builtin_amdgcn_mfma_f32_16x16x32_bf16(a0, b0, acc[0][0], 0, 0, 0);
                acc[0][1] = __builtin_amdgcn_mfma_f32_16x16x32_bf16(a0, b1, acc[0][1], 0, 0, 0);
                acc[1][0] = __builtin_amdgcn_mfma_f32_16x16x32_bf16(a1, b0, acc[1][0], 0, 0, 0);
                acc[1][1] = __builtin_amdgcn_mfma_f32_16x16x32_bf16(a1, b1, acc[1][1], 0, 0, 0);
            }
        }
        __builtin_amdgcn_sched_barrier(0);
        __builtin_amdgcn_s_barrier();
    }
#undef STAGE_CD

    // cross-wave K-reduce via LDS scratch (all gl16 drained by peeled vmcnt(0)).
    char* scr = &xs[1][0][0];
    if (ks == 1) {
        char* p = scr + (wv & 3) * 4096 + lane * 64;
        *(f32x4*)(p +  0) = acc[0][0];
        *(f32x4*)(p + 16) = acc[0][1];
        *(f32x4*)(p + 32) = acc[1][0];
        *(f32x4*)(p + 48) = acc[1][1];
    }
    __syncthreads();
    if (ks == 0) {
        const char* p = scr + (wv & 3) * 4096 + lane * 64;
        acc[0][0] += *(const f32x4*)(p +  0);
        acc[0][1] += *(const f32x4*)(p + 16);
        acc[1][0] += *(const f32x4*)(p + 32);
        acc[1][1] += *(const f32x4*)(p + 48);

        int h = R0 + lr;
        #pragma unroll
        for (int nt = 0; nt < 2; ++nt) {
            int colp = colh * 32 + nt * 16 + lo + 1;
            short* ob = tp2 + ((size_t)(b * 66 + h + 1) * 80 + colp) * 32;
            #pragma unroll
            for (int mt = 0; mt < 2; ++mt) {
                f32x4 bd4 = *(const f32x4*)(bd_eff + b * 32 + mt * 16 + hi * 4);
                short4v sv;
                #pragma unroll
                for (int j = 0; j < 4; ++j) {
                    float f = acc[mt][nt][j] + bd4[j];
                    f = f > 0.f ? f : 0.2f * f;
                    sv[j] = f2bf(f);
                }
                int sl = mt * 2 + (hi >> 1);
                int slp = sl ^ (colp & 3);
                *(short4v*)(ob + slp * 8 + (hi & 1) * 4) = sv;
            }
        }
    }
}

// ---------------------------------------------------------------------------
// Kernel 3: conv_up + residual, A-staged pipeline (unchanged from R11).
// ---------------------------------------------------------------------------
__global__ __launch_bounds__(256, 3) void k_conv_up(const short* __restrict__ tp2,
                                                    const short* __restrict__ wu_frag,
                                                    const float* __restrict__ content,
                                                    const float* __restrict__ bu,
                                                    float* __restrict__ out) {
    __shared__ __align__(16) short tl[10240];     // 4 x 80 x 32
    __shared__ __align__(16) char au[3][8192];    // [buf][8 g][1KB frag]
    int d = blockIdx.x;                 // 1024
    int nb = (d & 7) * 128 + (d >> 3);  // XCD x <-> batch x
    int b = nb >> 7, ocq = (nb >> 5) & 3, hb = nb & 31;
    int t = threadIdx.x, lane = t & 63, wv = t >> 6;
    int lr = wv >> 1, oh = wv & 1;
    int lo = lane & 15, hi = lane >> 4;
    int Ob = ocq * 128 + oh * 64;
    int R0 = 2 * hb;

    const char* sbase = (const char*)tp2 + ((size_t)(b * 66 + R0) * 80) * 64;
    #pragma unroll
    for (int i = 0; i < 5; ++i)
        gl16(sbase + (wv * 5 + i) * 1024 + lane * 16, (char*)tl + (wv * 5 + i) * 1024);

    // A source: g-frags [ocq*8 .. ocq*8+8) per kpos; kpos stride = 32 KB.
    const char* abase = (const char*)wu_frag + ((size_t)(b * 9) * 32 + ocq * 8) * 1024;
    #pragma unroll
    for (int k0 = 0; k0 < 2; ++k0)        // prologue: stage A[0], A[1]
        #pragma unroll
        for (int i = 0; i < 2; ++i)
            gl16(abase + (size_t)k0 * 32768 + (wv * 2 + i) * 1024 + lane * 16,
                 au[k0] + (wv * 2 + i) * 1024);

    asm volatile("s_waitcnt vmcnt(0)" ::: "memory");
    __builtin_amdgcn_sched_barrier(0);
    __builtin_amdgcn_s_barrier();
    __builtin_amdgcn_sched_barrier(0);

    f32x4 acc[4][4] = {};
    const int aoff = oh * 4096 + lo * 64 + hi * 16;   // wave's byte base in au[]

    #pragma unroll
    for (int kh = 0; kh < 3; ++kh) {
        #pragma unroll
        for (int kw = 0; kw < 3; ++kw) {
            const int kpos = kh * 3 + kw;
            if (kpos < 7) {
                #pragma unroll
                for (int i = 0; i < 2; ++i)
                    gl16(abase + (size_t)(kpos + 2) * 32768 + (wv * 2 + i) * 1024
                             + lane * 16,
                         au[(kpos + 2) % 3] + (wv * 2 + i) * 1024);
                asm volatile("s_waitcnt vmcnt(4)" ::: "memory");
            } else if (kpos == 7) {
                asm volatile("s_waitcnt vmcnt(2)" ::: "memory");
            } else {
                asm volatile("s_waitcnt vmcnt(0)" ::: "memory");
            }
            __builtin_amdgcn_sched_barrier(0);
            __builtin_amdgcn_s_barrier();
            __builtin_amdgcn_sched_barrier(0);

            const char* ab = au[kpos % 3];
            short8 bf0, bf1, bf2, bf3;
            #pragma unroll
            for (int nt = 0; nt < 4; ++nt) {
                int g = nt * 16 + lo + kw;                 // padded col 0..65
                short8 bf = *(const short8*)(tl + ((lr + kh) * 80 + g) * 32
                                                + ((hi ^ (g & 3)) << 3));
                if (nt == 0) bf0 = bf; else if (nt == 1) bf1 = bf;
                else if (nt == 2) bf2 = bf; else bf3 = bf;
            }
            #pragma unroll
            for (int mt = 0; mt < 4; ++mt) {
                short8 af = *(const short8*)(ab + mt * 1024 + aoff);
                acc[mt][0] = __builtin_amdgcn_mfma_f32_16x16x32_bf16(af, bf0, acc[mt][0], 0, 0, 0);
                acc[mt][1] = __builtin_amdgcn_mfma_f32_16x16x32_bf16(af, bf1, acc[mt][1], 0, 0, 0);
                acc[mt][2] = __builtin_amdgcn_mfma_f32_16x16x32_bf16(af, bf2, acc[mt][2], 0, 0, 0);
                acc[mt][3] = __builtin_amdgcn_mfma_f32_16x16x32_bf16(af, bf3, acc[mt][3], 0, 0, 0);
            }
            __builtin_amdgcn_sched_barrier(0);
            __builtin_amdgcn_s_barrier();
        }
    }

    int h = R0 + lr;
    #pragma unroll
    for (int mt = 0; mt < 4; ++mt) {
        f32x4 bu4 = *(const f32x4*)(bu + Ob + mt * 16 + hi * 4);
        #pragma unroll
        for (int nt = 0; nt < 4; ++nt) {
            int px = nt * 16 + lo;
            #pragma unroll
            for (int j = 0; j < 4; ++j) {
                int O = Ob + mt * 16 + hi * 4 + j;
                size_t gidx = (((size_t)(b * 512 + O) * 64) + h) * 64 + px;
                out[gidx] = acc[mt][nt][j] + content[gidx] + bu4[j];
            }
        }
    }
}

// ---------------------------------------------------------------------------
extern "C" void kernel_launch(void* const* d_in, const int* in_sizes, int n_in,
                              void* d_out, int out_size, void* d_ws, size_t ws_size,
                              hipStream_t stream) {
    const float* content = (const float*)d_in[0];
    const float* f1      = (const float*)d_in[1];
    const float* f2      = (const float*)d_in[2];
    const float* wd      = (const float*)d_in[3];
    const float* bd      = (const float*)d_in[4];
    const float* wu      = (const float*)d_in[5];
    const float* bu      = (const float*)d_in[6];
    float* out = (float*)d_out;

    char* ws = (char*)d_ws;
    // layout (bytes):
    //   xTc    [8][8][66][66][64] bf16 : 35,684,352
    //   wd_frag                        :  2,359,296
    //   wu_frag                        :  2,359,296
    //   bd_eff                         :      1,024
    //   tp2    [8][66][80][32] bf16    :  2,703,360   (total ~43.1 MiB)
    short* xTc     = (short*)(ws);
    short* wd_frag = (short*)(ws + 35684352);
    short* wu_frag = (short*)(ws + 38043648);
    float* bd_eff  = (float*)(ws + 40402944);
    short* tp2     = (short*)(ws + 40403968);

    k_prep     <<<dim3(2602), dim3(256), 0, stream>>>(content, f1, f2, wd, bd, wu,
                                                      xTc, wd_frag, wu_frag,
                                                      bd_eff, tp2);
    k_conv_down<<<dim3(256),  dim3(512), 0, stream>>>((const char*)xTc,
                                                      (const char*)wd_frag,
                                                      bd_eff, tp2);
    k_conv_up  <<<dim3(1024), dim3(256), 0, stream>>>(tp2, wu_frag, content, bu, out);
}